// Round 10
// baseline (499.302 us; speedup 1.0000x reference)
//
#include <hip/hip_runtime.h>
#include <hip/hip_bf16.h>

#define NN 50000
#define NE 1600000
#define FF 128
#define CC 16
#define NB ((NN + 63) / 64)       // 782 dst-buckets of 64 nodes
#define NBLK 128                  // partition blocks for the sort
#define CH ((NE + NBLK - 1) / NBLK)   // 12500 edges per partition block

using bf16 = __hip_bfloat16;
using bf16x8 = __attribute__((ext_vector_type(8))) short;   // 8 bf16 = 4 VGPRs
using f32x4  = __attribute__((ext_vector_type(4))) float;

// Runtime-dtype load: isbf selects bf16 vs f32 interpretation of p.
static __device__ __forceinline__ float ldf(const void* p, int i, int isbf){
    return isbf ? __bfloat162float(((const bf16*)p)[i]) : ((const float*)p)[i];
}
static __device__ __forceinline__ float bflo(unsigned u){
    union{unsigned x; float f;} c; c.x = u << 16; return c.f;
}
static __device__ __forceinline__ float bfhi(unsigned u){
    union{unsigned x; float f;} c; c.x = u & 0xFFFF0000u; return c.f;
}
static __device__ __forceinline__ unsigned short f2bfu(float v){
    bf16 b = __float2bfloat16(v);
    union{bf16 b; unsigned short u;} c; c.b = b; return c.u;
}

// ---------------- dtype detector ----------------
__global__ __launch_bounds__(256) void k_detect(const unsigned short* __restrict__ u,
                                                int* __restrict__ flag){
    int t = threadIdx.x;
    unsigned short lo = u[2 * t];
    int e = (lo >> 7) & 0xFF;
    int sane = (e >= 117 && e <= 137) ? 1 : 0;
    __shared__ int cnt;
    if (t == 0) cnt = 0;
    __syncthreads();
    atomicAdd(&cnt, sane);
    __syncthreads();
    if (t == 0) *flag = (cnt >= 128) ? 1 : 0;   // 1 => bf16 data
}

__global__ __launch_bounds__(256) void k_zero(int* __restrict__ p, int n){
    int i = blockIdx.x * 256 + threadIdx.x;
    if (i < n) p[i] = 0;
}

// ---------------- W prep: Wt[feat][k] = bf16(W[k][feat]) for W1, W2 ----------------
__global__ __launch_bounds__(256) void k_wprep(const void* __restrict__ W1, const void* __restrict__ W2,
                                               const int* __restrict__ dflag, unsigned short* __restrict__ wtg){
    const int isbf = *dflag;
    int idx = blockIdx.x * 256 + threadIdx.x;   // 0 .. 32767
    int l = idx >> 14;                          // 0: W1, 1: W2
    int e = idx & 16383;
    int f = e >> 7, k = e & 127;
    const void* W = l ? W2 : W1;
    wtg[idx] = f2bfu(ldf(W, k * FF + f, isbf));
}

// ---------------- CSR build: hierarchical counting sort by dst ----------------

__global__ __launch_bounds__(256) void k_bcount(const int* __restrict__ dst, int* __restrict__ bcounts,
                                                int* __restrict__ bh){
    __shared__ int hist[NB];
    const int t = threadIdx.x, b = blockIdx.x;
    for (int i = t; i < NB; i += 256) hist[i] = 0;
    __syncthreads();
    const int beg = b * CH, end = (beg + CH < NE) ? beg + CH : NE;
    for (int i = beg + t; i < end; i += 256){
        int d = dst[i];
        if ((unsigned)d >= NN) d = 0;
        atomicAdd(&hist[d >> 6], 1);
    }
    __syncthreads();
    for (int k = t; k < NB; k += 256){
        int v = hist[k];
        bh[k * NBLK + b] = v;
        if (v) atomicAdd(&bcounts[k], v);
    }
}

__global__ __launch_bounds__(256) void k_bscan(const int* __restrict__ bcounts, int* __restrict__ bbase,
                                               int* __restrict__ rowptr){
    __shared__ int s[256];
    const int t = threadIdx.x;
    constexpr int PT = (NB + 255) / 256;   // 4
    int loc[PT];
    int sum = 0;
    #pragma unroll
    for (int i = 0; i < PT; i++){
        int idx = t * PT + i;
        int v = (idx < NB) ? bcounts[idx] : 0;
        loc[i] = sum;
        sum += v;
    }
    s[t] = sum; __syncthreads();
    for (int off = 1; off < 256; off <<= 1){
        int x = (t >= off) ? s[t - off] : 0;
        __syncthreads();
        s[t] += x;
        __syncthreads();
    }
    int base = (t > 0) ? s[t - 1] : 0;
    #pragma unroll
    for (int i = 0; i < PT; i++){
        int idx = t * PT + i;
        if (idx < NB) bbase[idx] = base + loc[i];
    }
    if (t == 255){
        bbase[NB] = s[255];      // == NE
        rowptr[NN] = s[255];
    }
}

// Per-bucket offsets: wave-per-bucket shfl scan over the 128 per-block counts.
__global__ __launch_bounds__(256) void k_boffset(const int* __restrict__ bbase, int* __restrict__ bh){
    int k = blockIdx.x * 4 + (threadIdx.x >> 6);
    int lane = threadIdx.x & 63;
    if (k >= NB) return;
    int v0 = bh[k * NBLK + 2 * lane];
    int v1 = bh[k * NBLK + 2 * lane + 1];
    int s = v0 + v1;
    #pragma unroll
    for (int off = 1; off < 64; off <<= 1){
        int x = __shfl_up(s, off);
        if (lane >= off) s += x;
    }
    int base = bbase[k] + s - (v0 + v1);   // exclusive prefix of pair sums
    bh[k * NBLK + 2 * lane]     = base;
    bh[k * NBLK + 2 * lane + 1] = base + v0;
}

__global__ __launch_bounds__(256) void k_bucket(const int* __restrict__ src, const int* __restrict__ dst,
                                                const int* __restrict__ bh, unsigned* __restrict__ bpairs){
    __shared__ int cur[NB];
    const int t = threadIdx.x, b = blockIdx.x;
    for (int k = t; k < NB; k += 256) cur[k] = bh[k * NBLK + b];
    __syncthreads();
    const int beg = b * CH, end = (beg + CH < NE) ? beg + CH : NE;
    for (int i = beg + t; i < end; i += 256){
        int s = src[i];
        int d = dst[i];
        if ((unsigned)s >= NN) s = 0;
        if ((unsigned)d >= NN) d = 0;
        int p = atomicAdd(&cur[d >> 6], 1);
        if ((unsigned)p < NE) bpairs[p] = (unsigned)s | ((unsigned)(d & 63) << 16);
    }
}

__global__ __launch_bounds__(256) void k_bsort(const unsigned* __restrict__ bpairs, const int* __restrict__ bbase,
                                               int* __restrict__ rowptr, int* __restrict__ csrsrc){
    __shared__ int cnt[64];
    __shared__ int cur[64];
    const int t = threadIdx.x;
    const int b = blockIdx.x;
    const int base = bbase[b];
    const int endb = bbase[b + 1];
    if (t < 64) cnt[t] = 0;
    __syncthreads();
    for (int i = base + t; i < endb; i += 256)
        atomicAdd(&cnt[bpairs[i] >> 16], 1);
    __syncthreads();
    if (t < 64){   // wave 0 exactly: 64-lane exclusive scan via shfl
        int v = cnt[t];
        int inc = v;
        #pragma unroll
        for (int off = 1; off < 64; off <<= 1){
            int x = __shfl_up(inc, off);
            if (t >= off) inc += x;
        }
        int excl = inc - v;
        cur[t] = excl;
        int d = b * 64 + t;
        if (d < NN) rowptr[d] = base + excl;
    }
    __syncthreads();
    for (int i = base + t; i < endb; i += 256){
        unsigned pr = bpairs[i];
        int p = atomicAdd(&cur[pr >> 16], 1);
        csrsrc[base + p] = (int)(pr & 0xFFFFu);
    }
}

// ---------------- MFMA GEMM (layers 1-2): ft = X @ W, bf16 in / f32 acc / bf16 out ----------------

#define XPAD 136   // 17*8: keeps 16B alignment, breaks bank stride

template<bool XDYN>
__global__ __launch_bounds__(256) void k_mgemm(const void* __restrict__ X, const unsigned short* __restrict__ wtg,
                                               const void* __restrict__ al, const void* __restrict__ ar,
                                               const int* __restrict__ dflag, bf16* __restrict__ ft,
                                               float* __restrict__ el, float* __restrict__ er){
    __shared__ unsigned short xs[64 * XPAD];
    __shared__ unsigned short wt[128 * XPAD];
    const int isbf = *dflag;
    const int t  = threadIdx.x;
    const int n0 = blockIdx.x * 64;

    for (int i2 = t; i2 < 8192; i2 += 256){
        unsigned v = ((const unsigned*)wtg)[i2];
        int r = i2 >> 6, c2 = (i2 & 63) * 2;
        *(unsigned*)&wt[r * XPAD + c2] = v;
    }
    for (int i2 = t; i2 < 4096; i2 += 256){
        int r = i2 >> 6, c2 = (i2 & 63) * 2;
        int n = n0 + r;
        float v0 = 0.f, v1 = 0.f;
        if (n < NN){
            if (XDYN){ v0 = ldf(X, n * FF + c2, isbf); v1 = ldf(X, n * FF + c2 + 1, isbf); }
            else     { v0 = ((const float*)X)[n * FF + c2]; v1 = ((const float*)X)[n * FF + c2 + 1]; }
        }
        unsigned pk = (unsigned)f2bfu(v0) | ((unsigned)f2bfu(v1) << 16);
        *(unsigned*)&xs[r * XPAD + c2] = pk;
    }
    __syncthreads();

    const int wv = t >> 6;
    const int lane = t & 63;
    const int quad = lane >> 4;
    const int mcol = lane & 15;

    bf16x8 afr[4];
    const unsigned short* xrow = &xs[(wv * 16 + mcol) * XPAD + quad * 8];
    #pragma unroll
    for (int kt = 0; kt < 4; kt++)
        afr[kt] = *(const bf16x8*)(xrow + kt * 32);

    float elp[4] = {0.f,0.f,0.f,0.f}, erp[4] = {0.f,0.f,0.f,0.f};

    #pragma unroll
    for (int f = 0; f < 8; f++){
        f32x4 acc = {0.f, 0.f, 0.f, 0.f};
        const unsigned short* wrow = &wt[(f * 16 + mcol) * XPAD + quad * 8];
        #pragma unroll
        for (int kt = 0; kt < 4; kt++){
            bf16x8 bfr = *(const bf16x8*)(wrow + kt * 32);
            acc = __builtin_amdgcn_mfma_f32_16x16x32_bf16(afr[kt], bfr, acc, 0, 0, 0);
        }
        int col = f * 16 + mcol;
        float alv = ldf(al, col, isbf);
        float arv = ldf(ar, col, isbf);
        #pragma unroll
        for (int reg = 0; reg < 4; reg++){
            int node = n0 + wv * 16 + quad * 4 + reg;
            float v = acc[reg];
            if (node < NN) ft[node * FF + col] = __float2bfloat16(v);
            elp[reg] += v * alv;
            erp[reg] += v * arv;
        }
    }

    #pragma unroll
    for (int reg = 0; reg < 4; reg++){
        float pl = elp[reg], pr = erp[reg];
        #pragma unroll
        for (int off = 1; off < 16; off <<= 1){
            pl += __shfl_xor(pl, off);
            pr += __shfl_xor(pr, off);
        }
        int node = n0 + wv * 16 + quad * 4 + reg;
        if (mcol == 0 && node < NN){ el[node] = pl; er[node] = pr; }
    }
}

// ---------------- layer-3 GEMM (vector, OUT=16) + fused el/er ----------------
// BN=64 nodes/block, W3 transposed + staged in LDS, k-loop unrolled x4 (b128 reads).

__global__ __launch_bounds__(256) void k_gemm3(const float* __restrict__ X, const void* __restrict__ W,
                                               const void* __restrict__ al, const void* __restrict__ ar,
                                               const int* __restrict__ dflag, float* __restrict__ ft,
                                               float* __restrict__ el, float* __restrict__ er){
    __shared__ float xs[64][132];   // node-major, stride 132 floats (16B-aligned rows)
    __shared__ float wst[16][132];  // W3 transposed [feat][k]
    const int isbf = *dflag;
    const int t  = threadIdx.x;
    const int n0 = blockIdx.x * 64;

    for (int idx = t; idx < 2048; idx += 256){
        int k = idx >> 4, f = idx & 15;
        wst[f][k] = ldf(W, k * CC + f, isbf);
    }
    for (int idx = t; idx < 8192; idx += 256){
        int r = idx >> 7, c = idx & 127;
        int n = n0 + r;
        xs[r][c] = (n < NN) ? X[n * FF + c] : 0.f;
    }
    __syncthreads();

    const int tx = t & 15;    // output feature
    const int rg = t >> 4;    // node group (4 nodes)
    float acc[4] = {0.f,0.f,0.f,0.f};
    for (int k = 0; k < 128; k += 4){
        float4 wv = *(const float4*)&wst[tx][k];
        #pragma unroll
        for (int i = 0; i < 4; i++){
            float4 xv = *(const float4*)&xs[rg * 4 + i][k];
            acc[i] += wv.x * xv.x + wv.y * xv.y + wv.z * xv.z + wv.w * xv.w;
        }
    }

    float alv = ldf(al, tx, isbf);
    float arv = ldf(ar, tx, isbf);
    #pragma unroll
    for (int i = 0; i < 4; i++){
        int n = n0 + rg * 4 + i;
        if (n < NN) ft[n * CC + tx] = acc[i];
        float pl = acc[i] * alv, pr = acc[i] * arv;
        #pragma unroll
        for (int off = 1; off < 16; off <<= 1){
            pl += __shfl_xor(pl, off);
            pr += __shfl_xor(pr, off);
        }
        if (tx == 0 && n < NN){ el[n] = pl; er[n] = pr; }
    }
}

// ---------------- Aggregation (128 feats, bf16 ft): 16-lane edge groups ----------------
// One wave per dst node. Pass 1: parallel logits/max/weights/lsum. Pass 2:
// 4 edges per wave-load (16 lanes x dwordx4 = one 256B row each), 4-deep pipeline.

__global__ __launch_bounds__(256) void k_agg128(const void* __restrict__ ftv, const float* __restrict__ el,
                                                const float* __restrict__ er, const int* __restrict__ rowptr,
                                                const int* __restrict__ csrsrc, const void* __restrict__ bias,
                                                const int* __restrict__ dflag, float* __restrict__ outp){
    const int isbf = *dflag;
    int lane = threadIdx.x & 63;
    int n = blockIdx.x * 4 + (threadIdx.x >> 6);
    if (n >= NN) return;
    int beg = rowptr[n], end = rowptr[n + 1];
    beg = (beg < 0) ? 0 : (beg > NE ? NE : beg);
    end = (end < beg) ? beg : (end > NE ? NE : end);
    int deg = end - beg;
    float erd = er[n];

    // Pass 1
    float m = -3.4e38f;
    int   s_c = 0;
    float e_c = 0.f;
    for (int i = beg + lane; i < end; i += 64){
        int s = csrsrc[i];
        if ((unsigned)s >= NN) s = 0;
        float e = el[s] + erd;
        e = (e >= 0.f) ? e : 0.2f * e;
        if (i < beg + 64){ s_c = s; e_c = e; }
        m = fmaxf(m, e);
    }
    #pragma unroll
    for (int off = 32; off; off >>= 1) m = fmaxf(m, __shfl_xor(m, off));

    int jmax = (deg < 64) ? deg : 64;
    float w_c = (lane < jmax) ? __expf(e_c - m) : 0.f;
    float lsum = w_c;
    #pragma unroll
    for (int off = 32; off; off >>= 1) lsum += __shfl_xor(lsum, off);

    // Pass 2: 16-lane groups; group g handles edge 4b+g of batch b.
    const uint4* ftq = (const uint4*)ftv;     // row n at ftq[n*16 + fl]
    const int g  = lane >> 4;
    const int fl = lane & 15;
    float a8[8];
    #pragma unroll
    for (int i = 0; i < 8; i++) a8[i] = 0.f;

    int nbatch = (jmax + 3) >> 2;     // <= 16
    float wq[4]; uint4 uq[4];
    #pragma unroll
    for (int q = 0; q < 4; q++){
        int eidx = (q * 4 + g) & 63;
        int s = __shfl(s_c, eidx);
        wq[q] = (q < nbatch) ? __shfl(w_c, eidx) : 0.f;
        uq[q] = ftq[(unsigned)s * 16 + fl];
    }
    for (int b = 0; b < nbatch; b++){
        float w = wq[b & 3];
        uint4 u = uq[b & 3];
        int bn = b + 4;
        if (bn < nbatch){
            int eidx = (bn * 4 + g) & 63;
            int s = __shfl(s_c, eidx);
            wq[b & 3] = __shfl(w_c, eidx);
            uq[b & 3] = ftq[(unsigned)s * 16 + fl];
        } else {
            wq[b & 3] = 0.f;
        }
        a8[0] += w * bflo(u.x); a8[1] += w * bfhi(u.x);
        a8[2] += w * bflo(u.y); a8[3] += w * bfhi(u.y);
        a8[4] += w * bflo(u.z); a8[5] += w * bfhi(u.z);
        a8[6] += w * bflo(u.w); a8[7] += w * bfhi(u.w);
    }

    // Rare tail (deg > 64): wave-uniform; only group 0 accumulates features.
    for (int i = beg + 64; i < end; ++i){
        int s = csrsrc[i];
        if ((unsigned)s >= NN) s = 0;
        float e = el[s] + erd;
        e = (e >= 0.f) ? e : 0.2f * e;
        float w = __expf(e - m);
        lsum += w;
        if (g == 0){
            uint4 u = ftq[(unsigned)s * 16 + fl];
            a8[0] += w * bflo(u.x); a8[1] += w * bfhi(u.x);
            a8[2] += w * bflo(u.y); a8[3] += w * bfhi(u.y);
            a8[4] += w * bflo(u.z); a8[5] += w * bfhi(u.z);
            a8[6] += w * bflo(u.w); a8[7] += w * bfhi(u.w);
        }
    }

    // Combine the 4 edge groups.
    #pragma unroll
    for (int i = 0; i < 8; i++){
        a8[i] += __shfl_xor(a8[i], 16);
        a8[i] += __shfl_xor(a8[i], 32);
    }
    float inv = 1.f / ((lsum > 0.f) ? lsum : 1.f);
    if (lane < 16){
        float4 o0, o1;
        o0.x = fmaxf(a8[0] * inv + ldf(bias, fl * 8 + 0, isbf), 0.f);
        o0.y = fmaxf(a8[1] * inv + ldf(bias, fl * 8 + 1, isbf), 0.f);
        o0.z = fmaxf(a8[2] * inv + ldf(bias, fl * 8 + 2, isbf), 0.f);
        o0.w = fmaxf(a8[3] * inv + ldf(bias, fl * 8 + 3, isbf), 0.f);
        o1.x = fmaxf(a8[4] * inv + ldf(bias, fl * 8 + 4, isbf), 0.f);
        o1.y = fmaxf(a8[5] * inv + ldf(bias, fl * 8 + 5, isbf), 0.f);
        o1.z = fmaxf(a8[6] * inv + ldf(bias, fl * 8 + 6, isbf), 0.f);
        o1.w = fmaxf(a8[7] * inv + ldf(bias, fl * 8 + 7, isbf), 0.f);
        ((float4*)outp)[n * 32 + fl * 2]     = o0;
        ((float4*)outp)[n * 32 + fl * 2 + 1] = o1;
    }
}

// ---------------- Aggregation (16 feats, f32 ft): 4-lane edge groups, final output ----------------

__global__ __launch_bounds__(256) void k_agg16(const float* __restrict__ ftv, const float* __restrict__ el,
                                               const float* __restrict__ er, const int* __restrict__ rowptr,
                                               const int* __restrict__ csrsrc, const void* __restrict__ bias,
                                               const int* __restrict__ dflag, void* __restrict__ outp){
    const int isbf = *dflag;
    int lane = threadIdx.x & 63;
    int n = blockIdx.x * 4 + (threadIdx.x >> 6);
    if (n >= NN) return;
    int beg = rowptr[n], end = rowptr[n + 1];
    beg = (beg < 0) ? 0 : (beg > NE ? NE : beg);
    end = (end < beg) ? beg : (end > NE ? NE : end);
    int deg = end - beg;
    float erd = er[n];

    float m = -3.4e38f;
    int   s_c = 0;
    float e_c = 0.f;
    for (int i = beg + lane; i < end; i += 64){
        int s = csrsrc[i];
        if ((unsigned)s >= NN) s = 0;
        float e = el[s] + erd;
        e = (e >= 0.f) ? e : 0.2f * e;
        if (i < beg + 64){ s_c = s; e_c = e; }
        m = fmaxf(m, e);
    }
    #pragma unroll
    for (int off = 32; off; off >>= 1) m = fmaxf(m, __shfl_xor(m, off));

    int jmax = (deg < 64) ? deg : 64;
    float w_c = (lane < jmax) ? __expf(e_c - m) : 0.f;
    float lsum = w_c;
    #pragma unroll
    for (int off = 32; off; off >>= 1) lsum += __shfl_xor(lsum, off);

    // 4-lane groups: 16 edges per batch, <=4 batches. Row = 4 lanes x float4.
    const float4* ftq = (const float4*)ftv;   // row n at ftq[n*4 + fl2]
    const int g   = lane >> 2;    // edge-in-batch 0..15
    const int fl2 = lane & 3;
    int nbatch = (jmax + 15) >> 4;    // <= 4
    float wq[4]; float4 uq[4];
    #pragma unroll
    for (int q = 0; q < 4; q++){
        int eidx = (q * 16 + g) & 63;
        int s = __shfl(s_c, eidx);
        wq[q] = (q < nbatch) ? __shfl(w_c, eidx) : 0.f;
        uq[q] = ftq[(unsigned)s * 4 + fl2];
    }
    float a4[4] = {0.f,0.f,0.f,0.f};
    #pragma unroll
    for (int q = 0; q < 4; q++){
        a4[0] += wq[q] * uq[q].x;
        a4[1] += wq[q] * uq[q].y;
        a4[2] += wq[q] * uq[q].z;
        a4[3] += wq[q] * uq[q].w;
    }
    // Rare tail (deg > 64): only group 0 accumulates.
    for (int i = beg + 64; i < end; ++i){
        int s = csrsrc[i];
        if ((unsigned)s >= NN) s = 0;
        float e = el[s] + erd;
        e = (e >= 0.f) ? e : 0.2f * e;
        float w = __expf(e - m);
        lsum += w;
        if (g == 0){
            float4 u = ftq[(unsigned)s * 4 + fl2];
            a4[0] += w * u.x; a4[1] += w * u.y; a4[2] += w * u.z; a4[3] += w * u.w;
        }
    }
    #pragma unroll
    for (int i = 0; i < 4; i++){
        a4[i] += __shfl_xor(a4[i], 4);
        a4[i] += __shfl_xor(a4[i], 8);
        a4[i] += __shfl_xor(a4[i], 16);
        a4[i] += __shfl_xor(a4[i], 32);
    }
    float inv = 1.f / ((lsum > 0.f) ? lsum : 1.f);
    if (lane < 4){
        float o0 = fmaxf(a4[0] * inv + ldf(bias, fl2 * 4 + 0, isbf), 0.f);
        float o1 = fmaxf(a4[1] * inv + ldf(bias, fl2 * 4 + 1, isbf), 0.f);
        float o2 = fmaxf(a4[2] * inv + ldf(bias, fl2 * 4 + 2, isbf), 0.f);
        float o3 = fmaxf(a4[3] * inv + ldf(bias, fl2 * 4 + 3, isbf), 0.f);
        if (isbf){
            uint2 pk;
            pk.x = (unsigned)f2bfu(o0) | ((unsigned)f2bfu(o1) << 16);
            pk.y = (unsigned)f2bfu(o2) | ((unsigned)f2bfu(o3) << 16);
            ((uint2*)outp)[n * 4 + fl2] = pk;
        } else {
            float4 o; o.x = o0; o.y = o1; o.z = o2; o.w = o3;
            ((float4*)outp)[n * 4 + fl2] = o;
        }
    }
}

// ---------------- host launch ----------------

static size_t align256(size_t x){ return (x + 255) & ~(size_t)255; }

extern "C" void kernel_launch(void* const* d_in, const int* in_sizes, int n_in,
                              void* d_out, int out_size, void* d_ws, size_t ws_size,
                              hipStream_t stream) {
    const void* feat = d_in[0];
    const int*  src  = (const int*)d_in[1];
    const int*  dst  = (const int*)d_in[2];
    const void* W1 = d_in[3];
    const void* al1= d_in[4];
    const void* ar1= d_in[5];
    const void* b1 = d_in[6];
    const void* W2 = d_in[7];
    const void* al2= d_in[8];
    const void* ar2= d_in[9];
    const void* b2 = d_in[10];
    const void* W3 = d_in[11];
    const void* al3= d_in[12];
    const void* ar3= d_in[13];
    const void* b3 = d_in[14];

    // workspace carve
    char* p = (char*)d_ws;
    size_t off = 0;
    auto carve = [&](size_t bytes)->void*{
        void* r = p + off;
        off += align256(bytes);
        return r;
    };
    float* ftA   = (float*)carve((size_t)NN * FF * 4);   // ft buffer: bf16 view (layers 1/2), f32 view (layer 3)
    float* hB    = (float*)carve((size_t)NN * FF * 4);   // hidden state; bpairs overlays it pre-layer-1
    float* el    = (float*)carve((size_t)NN * 4);
    float* er    = (float*)carve((size_t)NN * 4);
    int*   rowptr= (int*)  carve((size_t)(NN + 1) * 4);
    int*   csrsrc= (int*)  carve((size_t)NE * 4);
    int*   bcounts=(int*)  carve((size_t)NB * 4);
    int*   bbase  =(int*)  carve((size_t)(NB + 1) * 4);
    int*   bh     =(int*)  carve((size_t)NB * NBLK * 4);  // per-(bucket,block) hist/offsets, 400KB
    unsigned short* wtg = (unsigned short*)carve(2 * 16384 * 2);  // W1t,W2t bf16 [feat][k]
    int*   dflag  =(int*)  carve(256);
    unsigned* bpairs = (unsigned*)hB;   // overlay: consumed before hB is first written
    void*  ftb   = ftA;                 // bf16 ft view (layers 1-2); f32 ft3 view (layer 3)
    (void)ws_size; (void)n_in; (void)in_sizes; (void)out_size;

    dim3 b256(256);

    k_detect<<<dim3(1), b256, 0, stream>>>((const unsigned short*)feat, dflag);
    k_wprep<<<dim3(128), b256, 0, stream>>>(W1, W2, dflag, wtg);

    // CSR build via hierarchical counting sort
    k_zero<<<dim3((NB + 255) / 256), b256, 0, stream>>>(bcounts, NB);
    k_bcount<<<dim3(NBLK), b256, 0, stream>>>(dst, bcounts, bh);
    k_bscan<<<dim3(1), b256, 0, stream>>>(bcounts, bbase, rowptr);
    k_boffset<<<dim3((NB + 3) / 4), b256, 0, stream>>>(bbase, bh);
    k_bucket<<<dim3(NBLK), b256, 0, stream>>>(src, dst, bh, bpairs);
    k_bsort<<<dim3(NB), b256, 0, stream>>>(bpairs, bbase, rowptr, csrsrc);

    const int mg_grid   = (NN + 63) / 64;     // 782
    const int node_grid = (NN + 3) / 4;       // 12500

    // Layer 1
    k_mgemm<true><<<dim3(mg_grid), b256, 0, stream>>>(feat, wtg, al1, ar1, dflag, (bf16*)ftb, el, er);
    k_agg128<<<dim3(node_grid), b256, 0, stream>>>(ftb, el, er, rowptr, csrsrc, b1, dflag, hB);

    // Layer 2
    k_mgemm<false><<<dim3(mg_grid), b256, 0, stream>>>(hB, wtg + 16384, al2, ar2, dflag, (bf16*)ftb, el, er);
    k_agg128<<<dim3(node_grid), b256, 0, stream>>>(ftb, el, er, rowptr, csrsrc, b2, dflag, hB);

    // Layer 3
    k_gemm3<<<dim3(mg_grid), b256, 0, stream>>>(hB, W3, al3, ar3, dflag, (float*)ftb, el, er);
    k_agg16<<<dim3(node_grid), b256, 0, stream>>>((const float*)ftb, el, er, rowptr, csrsrc, b3, dflag, d_out);
}

// Round 11
// 429.458 us; speedup vs baseline: 1.1626x; 1.1626x over previous
//
#include <hip/hip_runtime.h>
#include <hip/hip_bf16.h>

#define NN 50000
#define NE 1600000
#define FF 128
#define CC 16
#define NB ((NN + 63) / 64)       // 782 dst-buckets of 64 nodes
#define NBLK 128                  // partition blocks for the sort
#define CH ((NE + NBLK - 1) / NBLK)   // 12500 edges per partition block

using bf16 = __hip_bfloat16;
using bf16x8 = __attribute__((ext_vector_type(8))) short;   // 8 bf16 = 4 VGPRs
using f32x4  = __attribute__((ext_vector_type(4))) float;

// Runtime-dtype load: isbf selects bf16 vs f32 interpretation of p.
static __device__ __forceinline__ float ldf(const void* p, int i, int isbf){
    return isbf ? __bfloat162float(((const bf16*)p)[i]) : ((const float*)p)[i];
}
static __device__ __forceinline__ float bflo(unsigned u){
    union{unsigned x; float f;} c; c.x = u << 16; return c.f;
}
static __device__ __forceinline__ float bfhi(unsigned u){
    union{unsigned x; float f;} c; c.x = u & 0xFFFF0000u; return c.f;
}
static __device__ __forceinline__ unsigned short f2bfu(float v){
    bf16 b = __float2bfloat16(v);
    union{bf16 b; unsigned short u;} c; c.b = b; return c.u;
}

// ---------------- dtype detector ----------------
__global__ __launch_bounds__(256) void k_detect(const unsigned short* __restrict__ u,
                                                int* __restrict__ flag){
    int t = threadIdx.x;
    unsigned short lo = u[2 * t];
    int e = (lo >> 7) & 0xFF;
    int sane = (e >= 117 && e <= 137) ? 1 : 0;
    __shared__ int cnt;
    if (t == 0) cnt = 0;
    __syncthreads();
    atomicAdd(&cnt, sane);
    __syncthreads();
    if (t == 0) *flag = (cnt >= 128) ? 1 : 0;   // 1 => bf16 data
}

__global__ __launch_bounds__(256) void k_zero(int* __restrict__ p, int n){
    int i = blockIdx.x * 256 + threadIdx.x;
    if (i < n) p[i] = 0;
}

// ---------------- W prep: Wt[feat][k] = bf16(W[k][feat]) for W1, W2 ----------------
__global__ __launch_bounds__(256) void k_wprep(const void* __restrict__ W1, const void* __restrict__ W2,
                                               const int* __restrict__ dflag, unsigned short* __restrict__ wtg){
    const int isbf = *dflag;
    int idx = blockIdx.x * 256 + threadIdx.x;   // 0 .. 32767
    int l = idx >> 14;                          // 0: W1, 1: W2
    int e = idx & 16383;
    int f = e >> 7, k = e & 127;
    const void* W = l ? W2 : W1;
    wtg[idx] = f2bfu(ldf(W, k * FF + f, isbf));
}

// ---------------- CSR build: hierarchical counting sort by dst ----------------

__global__ __launch_bounds__(256) void k_bcount(const int* __restrict__ dst, int* __restrict__ bcounts,
                                                int* __restrict__ bh){
    __shared__ int hist[NB];
    const int t = threadIdx.x, b = blockIdx.x;
    for (int i = t; i < NB; i += 256) hist[i] = 0;
    __syncthreads();
    const int beg = b * CH, end = (beg + CH < NE) ? beg + CH : NE;
    for (int i = beg + t; i < end; i += 256){
        int d = dst[i];
        if ((unsigned)d >= NN) d = 0;
        atomicAdd(&hist[d >> 6], 1);
    }
    __syncthreads();
    for (int k = t; k < NB; k += 256){
        int v = hist[k];
        bh[k * NBLK + b] = v;
        if (v) atomicAdd(&bcounts[k], v);
    }
}

__global__ __launch_bounds__(256) void k_bscan(const int* __restrict__ bcounts, int* __restrict__ bbase,
                                               int* __restrict__ rowptr){
    __shared__ int s[256];
    const int t = threadIdx.x;
    constexpr int PT = (NB + 255) / 256;   // 4
    int loc[PT];
    int sum = 0;
    #pragma unroll
    for (int i = 0; i < PT; i++){
        int idx = t * PT + i;
        int v = (idx < NB) ? bcounts[idx] : 0;
        loc[i] = sum;
        sum += v;
    }
    s[t] = sum; __syncthreads();
    for (int off = 1; off < 256; off <<= 1){
        int x = (t >= off) ? s[t - off] : 0;
        __syncthreads();
        s[t] += x;
        __syncthreads();
    }
    int base = (t > 0) ? s[t - 1] : 0;
    #pragma unroll
    for (int i = 0; i < PT; i++){
        int idx = t * PT + i;
        if (idx < NB) bbase[idx] = base + loc[i];
    }
    if (t == 255){
        bbase[NB] = s[255];      // == NE
        rowptr[NN] = s[255];
    }
}

// Per-bucket offsets: wave-per-bucket shfl scan over the 128 per-block counts.
__global__ __launch_bounds__(256) void k_boffset(const int* __restrict__ bbase, int* __restrict__ bh){
    int k = blockIdx.x * 4 + (threadIdx.x >> 6);
    int lane = threadIdx.x & 63;
    if (k >= NB) return;
    int v0 = bh[k * NBLK + 2 * lane];
    int v1 = bh[k * NBLK + 2 * lane + 1];
    int s = v0 + v1;
    #pragma unroll
    for (int off = 1; off < 64; off <<= 1){
        int x = __shfl_up(s, off);
        if (lane >= off) s += x;
    }
    int base = bbase[k] + s - (v0 + v1);   // exclusive prefix of pair sums
    bh[k * NBLK + 2 * lane]     = base;
    bh[k * NBLK + 2 * lane + 1] = base + v0;
}

__global__ __launch_bounds__(256) void k_bucket(const int* __restrict__ src, const int* __restrict__ dst,
                                                const int* __restrict__ bh, unsigned* __restrict__ bpairs){
    __shared__ int cur[NB];
    const int t = threadIdx.x, b = blockIdx.x;
    for (int k = t; k < NB; k += 256) cur[k] = bh[k * NBLK + b];
    __syncthreads();
    const int beg = b * CH, end = (beg + CH < NE) ? beg + CH : NE;
    for (int i = beg + t; i < end; i += 256){
        int s = src[i];
        int d = dst[i];
        if ((unsigned)s >= NN) s = 0;
        if ((unsigned)d >= NN) d = 0;
        int p = atomicAdd(&cur[d >> 6], 1);
        if ((unsigned)p < NE) bpairs[p] = (unsigned)s | ((unsigned)(d & 63) << 16);
    }
}

__global__ __launch_bounds__(256) void k_bsort(const unsigned* __restrict__ bpairs, const int* __restrict__ bbase,
                                               int* __restrict__ rowptr, int* __restrict__ csrsrc){
    __shared__ int cnt[64];
    __shared__ int cur[64];
    const int t = threadIdx.x;
    const int b = blockIdx.x;
    const int base = bbase[b];
    const int endb = bbase[b + 1];
    if (t < 64) cnt[t] = 0;
    __syncthreads();
    for (int i = base + t; i < endb; i += 256)
        atomicAdd(&cnt[bpairs[i] >> 16], 1);
    __syncthreads();
    if (t < 64){   // wave 0 exactly: 64-lane exclusive scan via shfl
        int v = cnt[t];
        int inc = v;
        #pragma unroll
        for (int off = 1; off < 64; off <<= 1){
            int x = __shfl_up(inc, off);
            if (t >= off) inc += x;
        }
        int excl = inc - v;
        cur[t] = excl;
        int d = b * 64 + t;
        if (d < NN) rowptr[d] = base + excl;
    }
    __syncthreads();
    for (int i = base + t; i < endb; i += 256){
        unsigned pr = bpairs[i];
        int p = atomicAdd(&cur[pr >> 16], 1);
        csrsrc[base + p] = (int)(pr & 0xFFFFu);
    }
}

// ---------------- MFMA GEMM (layers 1-2): ft = X @ W, bf16 in / f32 acc / bf16 out ----------------

#define XPAD 136   // 17*8: keeps 16B alignment, breaks bank stride

template<bool XDYN>
__global__ __launch_bounds__(256) void k_mgemm(const void* __restrict__ X, const unsigned short* __restrict__ wtg,
                                               const void* __restrict__ al, const void* __restrict__ ar,
                                               const int* __restrict__ dflag, bf16* __restrict__ ft,
                                               float* __restrict__ el, float* __restrict__ er){
    __shared__ unsigned short xs[64 * XPAD];
    __shared__ unsigned short wt[128 * XPAD];
    const int isbf = *dflag;
    const int t  = threadIdx.x;
    const int n0 = blockIdx.x * 64;

    for (int i2 = t; i2 < 8192; i2 += 256){
        unsigned v = ((const unsigned*)wtg)[i2];
        int r = i2 >> 6, c2 = (i2 & 63) * 2;
        *(unsigned*)&wt[r * XPAD + c2] = v;
    }
    for (int i2 = t; i2 < 4096; i2 += 256){
        int r = i2 >> 6, c2 = (i2 & 63) * 2;
        int n = n0 + r;
        float v0 = 0.f, v1 = 0.f;
        if (n < NN){
            if (XDYN){ v0 = ldf(X, n * FF + c2, isbf); v1 = ldf(X, n * FF + c2 + 1, isbf); }
            else     { v0 = ((const float*)X)[n * FF + c2]; v1 = ((const float*)X)[n * FF + c2 + 1]; }
        }
        unsigned pk = (unsigned)f2bfu(v0) | ((unsigned)f2bfu(v1) << 16);
        *(unsigned*)&xs[r * XPAD + c2] = pk;
    }
    __syncthreads();

    const int wv = t >> 6;
    const int lane = t & 63;
    const int quad = lane >> 4;
    const int mcol = lane & 15;

    bf16x8 afr[4];
    const unsigned short* xrow = &xs[(wv * 16 + mcol) * XPAD + quad * 8];
    #pragma unroll
    for (int kt = 0; kt < 4; kt++)
        afr[kt] = *(const bf16x8*)(xrow + kt * 32);

    float elp[4] = {0.f,0.f,0.f,0.f}, erp[4] = {0.f,0.f,0.f,0.f};

    #pragma unroll
    for (int f = 0; f < 8; f++){
        f32x4 acc = {0.f, 0.f, 0.f, 0.f};
        const unsigned short* wrow = &wt[(f * 16 + mcol) * XPAD + quad * 8];
        #pragma unroll
        for (int kt = 0; kt < 4; kt++){
            bf16x8 bfr = *(const bf16x8*)(wrow + kt * 32);
            acc = __builtin_amdgcn_mfma_f32_16x16x32_bf16(afr[kt], bfr, acc, 0, 0, 0);
        }
        int col = f * 16 + mcol;
        float alv = ldf(al, col, isbf);
        float arv = ldf(ar, col, isbf);
        #pragma unroll
        for (int reg = 0; reg < 4; reg++){
            int node = n0 + wv * 16 + quad * 4 + reg;
            float v = acc[reg];
            if (node < NN) ft[node * FF + col] = __float2bfloat16(v);
            elp[reg] += v * alv;
            erp[reg] += v * arv;
        }
    }

    #pragma unroll
    for (int reg = 0; reg < 4; reg++){
        float pl = elp[reg], pr = erp[reg];
        #pragma unroll
        for (int off = 1; off < 16; off <<= 1){
            pl += __shfl_xor(pl, off);
            pr += __shfl_xor(pr, off);
        }
        int node = n0 + wv * 16 + quad * 4 + reg;
        if (mcol == 0 && node < NN){ el[node] = pl; er[node] = pr; }
    }
}

// ---------------- layer-3 GEMM (vector, OUT=16, BN=16) + fused el/er ----------------
// Round-9 proven version: VGPR ~32, no spills. 16 nodes/block; X tile transposed in LDS.

__global__ __launch_bounds__(256) void k_gemm3(const float* __restrict__ X, const void* __restrict__ W,
                                               const void* __restrict__ al, const void* __restrict__ ar,
                                               const int* __restrict__ dflag, float* __restrict__ ft,
                                               float* __restrict__ el, float* __restrict__ er){
    constexpr int BN = 16;
    __shared__ float xs[FF][BN + 1];
    const int isbf = *dflag;
    const int t  = threadIdx.x;
    const int n0 = blockIdx.x * BN;

    for (int idx = t; idx < BN * FF; idx += 256){
        int r = idx >> 7;
        int c = idx & 127;
        int n = n0 + r;
        xs[c][r] = (n < NN) ? X[n * FF + c] : 0.f;
    }
    __syncthreads();

    const int tx = t & 15;    // output feature
    const int rg = t >> 4;    // node
    float acc = 0.f;
    if (isbf){
        const bf16* Wb = (const bf16*)W;
        for (int k = 0; k < FF; k++)
            acc += __bfloat162float(Wb[k * CC + tx]) * xs[k][rg];
    } else {
        const float* Wf = (const float*)W;
        for (int k = 0; k < FF; k++)
            acc += Wf[k * CC + tx] * xs[k][rg];
    }

    int n = n0 + rg;
    if (n < NN) ft[n * CC + tx] = acc;

    float alv = ldf(al, tx, isbf);
    float arv = ldf(ar, tx, isbf);
    float pl = acc * alv, pr = acc * arv;
    #pragma unroll
    for (int off = 1; off < 16; off <<= 1){
        pl += __shfl_xor(pl, off);
        pr += __shfl_xor(pr, off);
    }
    if (tx == 0 && n < NN){ el[n] = pl; er[n] = pr; }
}

// ---------------- Aggregation (128 feats, bf16 ft): 16-lane edge groups ----------------

__global__ __launch_bounds__(256) void k_agg128(const void* __restrict__ ftv, const float* __restrict__ el,
                                                const float* __restrict__ er, const int* __restrict__ rowptr,
                                                const int* __restrict__ csrsrc, const void* __restrict__ bias,
                                                const int* __restrict__ dflag, float* __restrict__ outp){
    const int isbf = *dflag;
    int lane = threadIdx.x & 63;
    int n = blockIdx.x * 4 + (threadIdx.x >> 6);
    if (n >= NN) return;
    int beg = rowptr[n], end = rowptr[n + 1];
    beg = (beg < 0) ? 0 : (beg > NE ? NE : beg);
    end = (end < beg) ? beg : (end > NE ? NE : end);
    int deg = end - beg;
    float erd = er[n];

    // Pass 1
    float m = -3.4e38f;
    int   s_c = 0;
    float e_c = 0.f;
    for (int i = beg + lane; i < end; i += 64){
        int s = csrsrc[i];
        if ((unsigned)s >= NN) s = 0;
        float e = el[s] + erd;
        e = (e >= 0.f) ? e : 0.2f * e;
        if (i < beg + 64){ s_c = s; e_c = e; }
        m = fmaxf(m, e);
    }
    #pragma unroll
    for (int off = 32; off; off >>= 1) m = fmaxf(m, __shfl_xor(m, off));

    int jmax = (deg < 64) ? deg : 64;
    float w_c = (lane < jmax) ? __expf(e_c - m) : 0.f;
    float lsum = w_c;
    #pragma unroll
    for (int off = 32; off; off >>= 1) lsum += __shfl_xor(lsum, off);

    // Pass 2: 16-lane groups; group g handles edge 4b+g of batch b.
    const uint4* ftq = (const uint4*)ftv;     // row n at ftq[n*16 + fl]
    const int g  = lane >> 4;
    const int fl = lane & 15;
    float a8[8];
    #pragma unroll
    for (int i = 0; i < 8; i++) a8[i] = 0.f;

    int nbatch = (jmax + 3) >> 2;     // <= 16
    float wq[4]; uint4 uq[4];
    #pragma unroll
    for (int q = 0; q < 4; q++){
        int eidx = (q * 4 + g) & 63;
        int s = __shfl(s_c, eidx);
        wq[q] = (q < nbatch) ? __shfl(w_c, eidx) : 0.f;
        uq[q] = ftq[(unsigned)s * 16 + fl];
    }
    for (int b = 0; b < nbatch; b++){
        float w = wq[b & 3];
        uint4 u = uq[b & 3];
        int bn = b + 4;
        if (bn < nbatch){
            int eidx = (bn * 4 + g) & 63;
            int s = __shfl(s_c, eidx);
            wq[b & 3] = __shfl(w_c, eidx);
            uq[b & 3] = ftq[(unsigned)s * 16 + fl];
        } else {
            wq[b & 3] = 0.f;
        }
        a8[0] += w * bflo(u.x); a8[1] += w * bfhi(u.x);
        a8[2] += w * bflo(u.y); a8[3] += w * bfhi(u.y);
        a8[4] += w * bflo(u.z); a8[5] += w * bfhi(u.z);
        a8[6] += w * bflo(u.w); a8[7] += w * bfhi(u.w);
    }

    // Rare tail (deg > 64): wave-uniform; only group 0 accumulates features.
    for (int i = beg + 64; i < end; ++i){
        int s = csrsrc[i];
        if ((unsigned)s >= NN) s = 0;
        float e = el[s] + erd;
        e = (e >= 0.f) ? e : 0.2f * e;
        float w = __expf(e - m);
        lsum += w;
        if (g == 0){
            uint4 u = ftq[(unsigned)s * 16 + fl];
            a8[0] += w * bflo(u.x); a8[1] += w * bfhi(u.x);
            a8[2] += w * bflo(u.y); a8[3] += w * bfhi(u.y);
            a8[4] += w * bflo(u.z); a8[5] += w * bfhi(u.z);
            a8[6] += w * bflo(u.w); a8[7] += w * bfhi(u.w);
        }
    }

    // Combine the 4 edge groups.
    #pragma unroll
    for (int i = 0; i < 8; i++){
        a8[i] += __shfl_xor(a8[i], 16);
        a8[i] += __shfl_xor(a8[i], 32);
    }
    float inv = 1.f / ((lsum > 0.f) ? lsum : 1.f);
    if (lane < 16){
        float4 o0, o1;
        o0.x = fmaxf(a8[0] * inv + ldf(bias, fl * 8 + 0, isbf), 0.f);
        o0.y = fmaxf(a8[1] * inv + ldf(bias, fl * 8 + 1, isbf), 0.f);
        o0.z = fmaxf(a8[2] * inv + ldf(bias, fl * 8 + 2, isbf), 0.f);
        o0.w = fmaxf(a8[3] * inv + ldf(bias, fl * 8 + 3, isbf), 0.f);
        o1.x = fmaxf(a8[4] * inv + ldf(bias, fl * 8 + 4, isbf), 0.f);
        o1.y = fmaxf(a8[5] * inv + ldf(bias, fl * 8 + 5, isbf), 0.f);
        o1.z = fmaxf(a8[6] * inv + ldf(bias, fl * 8 + 6, isbf), 0.f);
        o1.w = fmaxf(a8[7] * inv + ldf(bias, fl * 8 + 7, isbf), 0.f);
        ((float4*)outp)[n * 32 + fl * 2]     = o0;
        ((float4*)outp)[n * 32 + fl * 2 + 1] = o1;
    }
}

// ---------------- Aggregation (16 feats, f32 ft): 4-lane edge groups, final output ----------------

__global__ __launch_bounds__(256) void k_agg16(const float* __restrict__ ftv, const float* __restrict__ el,
                                               const float* __restrict__ er, const int* __restrict__ rowptr,
                                               const int* __restrict__ csrsrc, const void* __restrict__ bias,
                                               const int* __restrict__ dflag, void* __restrict__ outp){
    const int isbf = *dflag;
    int lane = threadIdx.x & 63;
    int n = blockIdx.x * 4 + (threadIdx.x >> 6);
    if (n >= NN) return;
    int beg = rowptr[n], end = rowptr[n + 1];
    beg = (beg < 0) ? 0 : (beg > NE ? NE : beg);
    end = (end < beg) ? beg : (end > NE ? NE : end);
    int deg = end - beg;
    float erd = er[n];

    float m = -3.4e38f;
    int   s_c = 0;
    float e_c = 0.f;
    for (int i = beg + lane; i < end; i += 64){
        int s = csrsrc[i];
        if ((unsigned)s >= NN) s = 0;
        float e = el[s] + erd;
        e = (e >= 0.f) ? e : 0.2f * e;
        if (i < beg + 64){ s_c = s; e_c = e; }
        m = fmaxf(m, e);
    }
    #pragma unroll
    for (int off = 32; off; off >>= 1) m = fmaxf(m, __shfl_xor(m, off));

    int jmax = (deg < 64) ? deg : 64;
    float w_c = (lane < jmax) ? __expf(e_c - m) : 0.f;
    float lsum = w_c;
    #pragma unroll
    for (int off = 32; off; off >>= 1) lsum += __shfl_xor(lsum, off);

    // 4-lane groups: 16 edges per batch, <=4 batches. Row = 4 lanes x float4.
    const float4* ftq = (const float4*)ftv;   // row n at ftq[n*4 + fl2]
    const int g   = lane >> 2;    // edge-in-batch 0..15
    const int fl2 = lane & 3;
    int nbatch = (jmax + 15) >> 4;    // <= 4
    float wq[4]; float4 uq[4];
    #pragma unroll
    for (int q = 0; q < 4; q++){
        int eidx = (q * 16 + g) & 63;
        int s = __shfl(s_c, eidx);
        wq[q] = (q < nbatch) ? __shfl(w_c, eidx) : 0.f;
        uq[q] = ftq[(unsigned)s * 4 + fl2];
    }
    float a4[4] = {0.f,0.f,0.f,0.f};
    #pragma unroll
    for (int q = 0; q < 4; q++){
        a4[0] += wq[q] * uq[q].x;
        a4[1] += wq[q] * uq[q].y;
        a4[2] += wq[q] * uq[q].z;
        a4[3] += wq[q] * uq[q].w;
    }
    // Rare tail (deg > 64): only group 0 accumulates.
    for (int i = beg + 64; i < end; ++i){
        int s = csrsrc[i];
        if ((unsigned)s >= NN) s = 0;
        float e = el[s] + erd;
        e = (e >= 0.f) ? e : 0.2f * e;
        float w = __expf(e - m);
        lsum += w;
        if (g == 0){
            float4 u = ftq[(unsigned)s * 4 + fl2];
            a4[0] += w * u.x; a4[1] += w * u.y; a4[2] += w * u.z; a4[3] += w * u.w;
        }
    }
    #pragma unroll
    for (int i = 0; i < 4; i++){
        a4[i] += __shfl_xor(a4[i], 4);
        a4[i] += __shfl_xor(a4[i], 8);
        a4[i] += __shfl_xor(a4[i], 16);
        a4[i] += __shfl_xor(a4[i], 32);
    }
    float inv = 1.f / ((lsum > 0.f) ? lsum : 1.f);
    if (lane < 4){
        float o0 = fmaxf(a4[0] * inv + ldf(bias, fl2 * 4 + 0, isbf), 0.f);
        float o1 = fmaxf(a4[1] * inv + ldf(bias, fl2 * 4 + 1, isbf), 0.f);
        float o2 = fmaxf(a4[2] * inv + ldf(bias, fl2 * 4 + 2, isbf), 0.f);
        float o3 = fmaxf(a4[3] * inv + ldf(bias, fl2 * 4 + 3, isbf), 0.f);
        if (isbf){
            uint2 pk;
            pk.x = (unsigned)f2bfu(o0) | ((unsigned)f2bfu(o1) << 16);
            pk.y = (unsigned)f2bfu(o2) | ((unsigned)f2bfu(o3) << 16);
            ((uint2*)outp)[n * 4 + fl2] = pk;
        } else {
            float4 o; o.x = o0; o.y = o1; o.z = o2; o.w = o3;
            ((float4*)outp)[n * 4 + fl2] = o;
        }
    }
}

// ---------------- host launch ----------------

static size_t align256(size_t x){ return (x + 255) & ~(size_t)255; }

extern "C" void kernel_launch(void* const* d_in, const int* in_sizes, int n_in,
                              void* d_out, int out_size, void* d_ws, size_t ws_size,
                              hipStream_t stream) {
    const void* feat = d_in[0];
    const int*  src  = (const int*)d_in[1];
    const int*  dst  = (const int*)d_in[2];
    const void* W1 = d_in[3];
    const void* al1= d_in[4];
    const void* ar1= d_in[5];
    const void* b1 = d_in[6];
    const void* W2 = d_in[7];
    const void* al2= d_in[8];
    const void* ar2= d_in[9];
    const void* b2 = d_in[10];
    const void* W3 = d_in[11];
    const void* al3= d_in[12];
    const void* ar3= d_in[13];
    const void* b3 = d_in[14];

    // workspace carve
    char* p = (char*)d_ws;
    size_t off = 0;
    auto carve = [&](size_t bytes)->void*{
        void* r = p + off;
        off += align256(bytes);
        return r;
    };
    float* ftA   = (float*)carve((size_t)NN * FF * 4);   // ft buffer: bf16 view (layers 1/2), f32 view (layer 3)
    float* hB    = (float*)carve((size_t)NN * FF * 4);   // hidden state; bpairs overlays it pre-layer-1
    float* el    = (float*)carve((size_t)NN * 4);
    float* er    = (float*)carve((size_t)NN * 4);
    int*   rowptr= (int*)  carve((size_t)(NN + 1) * 4);
    int*   csrsrc= (int*)  carve((size_t)NE * 4);
    int*   bcounts=(int*)  carve((size_t)NB * 4);
    int*   bbase  =(int*)  carve((size_t)(NB + 1) * 4);
    int*   bh     =(int*)  carve((size_t)NB * NBLK * 4);  // per-(bucket,block) hist/offsets, 400KB
    unsigned short* wtg = (unsigned short*)carve(2 * 16384 * 2);  // W1t,W2t bf16 [feat][k]
    int*   dflag  =(int*)  carve(256);
    unsigned* bpairs = (unsigned*)hB;   // overlay: consumed before hB is first written
    void*  ftb   = ftA;                 // bf16 ft view (layers 1-2); f32 ft3 view (layer 3)
    (void)ws_size; (void)n_in; (void)in_sizes; (void)out_size;

    dim3 b256(256);

    k_detect<<<dim3(1), b256, 0, stream>>>((const unsigned short*)feat, dflag);
    k_wprep<<<dim3(128), b256, 0, stream>>>(W1, W2, dflag, wtg);

    // CSR build via hierarchical counting sort
    k_zero<<<dim3((NB + 255) / 256), b256, 0, stream>>>(bcounts, NB);
    k_bcount<<<dim3(NBLK), b256, 0, stream>>>(dst, bcounts, bh);
    k_bscan<<<dim3(1), b256, 0, stream>>>(bcounts, bbase, rowptr);
    k_boffset<<<dim3((NB + 3) / 4), b256, 0, stream>>>(bbase, bh);
    k_bucket<<<dim3(NBLK), b256, 0, stream>>>(src, dst, bh, bpairs);
    k_bsort<<<dim3(NB), b256, 0, stream>>>(bpairs, bbase, rowptr, csrsrc);

    const int mg_grid   = (NN + 63) / 64;     // 782
    const int g3_grid   = (NN + 15) / 16;     // 3125
    const int node_grid = (NN + 3) / 4;       // 12500

    // Layer 1
    k_mgemm<true><<<dim3(mg_grid), b256, 0, stream>>>(feat, wtg, al1, ar1, dflag, (bf16*)ftb, el, er);
    k_agg128<<<dim3(node_grid), b256, 0, stream>>>(ftb, el, er, rowptr, csrsrc, b1, dflag, hB);

    // Layer 2
    k_mgemm<false><<<dim3(mg_grid), b256, 0, stream>>>(hB, wtg + 16384, al2, ar2, dflag, (bf16*)ftb, el, er);
    k_agg128<<<dim3(node_grid), b256, 0, stream>>>(ftb, el, er, rowptr, csrsrc, b2, dflag, hB);

    // Layer 3
    k_gemm3<<<dim3(g3_grid), b256, 0, stream>>>(hB, W3, al3, ar3, dflag, (float*)ftb, el, er);
    k_agg16<<<dim3(node_grid), b256, 0, stream>>>((const float*)ftb, el, er, rowptr, csrsrc, b3, dflag, d_out);
}

// Round 12
// 396.196 us; speedup vs baseline: 1.2602x; 1.0840x over previous
//
#include <hip/hip_runtime.h>
#include <hip/hip_bf16.h>

#define NN 50000
#define NE 1600000
#define FF 128
#define CC 16
#define NB ((NN + 63) / 64)       // 782 dst-buckets of 64 nodes
#define NBLK 128                  // partition blocks for the sort
#define CH ((NE + NBLK - 1) / NBLK)   // 12500 edges per partition block

using bf16 = __hip_bfloat16;
using bf16x8 = __attribute__((ext_vector_type(8))) short;   // 8 bf16 = 4 VGPRs
using f32x4  = __attribute__((ext_vector_type(4))) float;

// Runtime-dtype load: isbf selects bf16 vs f32 interpretation of p.
static __device__ __forceinline__ float ldf(const void* p, int i, int isbf){
    return isbf ? __bfloat162float(((const bf16*)p)[i]) : ((const float*)p)[i];
}
static __device__ __forceinline__ float bflo(unsigned u){
    union{unsigned x; float f;} c; c.x = u << 16; return c.f;
}
static __device__ __forceinline__ float bfhi(unsigned u){
    union{unsigned x; float f;} c; c.x = u & 0xFFFF0000u; return c.f;
}
static __device__ __forceinline__ unsigned short f2bfu(float v){
    bf16 b = __float2bfloat16(v);
    union{bf16 b; unsigned short u;} c; c.b = b; return c.u;
}

// ---------------- dtype detector ----------------
__global__ __launch_bounds__(256) void k_detect(const unsigned short* __restrict__ u,
                                                int* __restrict__ flag){
    int t = threadIdx.x;
    unsigned short lo = u[2 * t];
    int e = (lo >> 7) & 0xFF;
    int sane = (e >= 117 && e <= 137) ? 1 : 0;
    __shared__ int cnt;
    if (t == 0) cnt = 0;
    __syncthreads();
    atomicAdd(&cnt, sane);
    __syncthreads();
    if (t == 0) *flag = (cnt >= 128) ? 1 : 0;   // 1 => bf16 data
}

__global__ __launch_bounds__(256) void k_zero(int* __restrict__ p, int n){
    int i = blockIdx.x * 256 + threadIdx.x;
    if (i < n) p[i] = 0;
}

// ---------------- W prep: Wt[feat][k] = bf16(W[k][feat]) for W1, W2 ----------------
__global__ __launch_bounds__(256) void k_wprep(const void* __restrict__ W1, const void* __restrict__ W2,
                                               const int* __restrict__ dflag, unsigned short* __restrict__ wtg){
    const int isbf = *dflag;
    int idx = blockIdx.x * 256 + threadIdx.x;   // 0 .. 32767
    int l = idx >> 14;                          // 0: W1, 1: W2
    int e = idx & 16383;
    int f = e >> 7, k = e & 127;
    const void* W = l ? W2 : W1;
    wtg[idx] = f2bfu(ldf(W, k * FF + f, isbf));
}

// ---------------- CSR build: hierarchical counting sort by dst ----------------

__global__ __launch_bounds__(256) void k_bcount(const int* __restrict__ dst, int* __restrict__ bcounts,
                                                int* __restrict__ bh){
    __shared__ int hist[NB];
    const int t = threadIdx.x, b = blockIdx.x;
    for (int i = t; i < NB; i += 256) hist[i] = 0;
    __syncthreads();
    const int beg = b * CH, end = (beg + CH < NE) ? beg + CH : NE;
    for (int i = beg + t; i < end; i += 256){
        int d = dst[i];
        if ((unsigned)d >= NN) d = 0;
        atomicAdd(&hist[d >> 6], 1);
    }
    __syncthreads();
    for (int k = t; k < NB; k += 256){
        int v = hist[k];
        bh[k * NBLK + b] = v;
        if (v) atomicAdd(&bcounts[k], v);
    }
}

__global__ __launch_bounds__(256) void k_bscan(const int* __restrict__ bcounts, int* __restrict__ bbase,
                                               int* __restrict__ rowptr){
    __shared__ int s[256];
    const int t = threadIdx.x;
    constexpr int PT = (NB + 255) / 256;   // 4
    int loc[PT];
    int sum = 0;
    #pragma unroll
    for (int i = 0; i < PT; i++){
        int idx = t * PT + i;
        int v = (idx < NB) ? bcounts[idx] : 0;
        loc[i] = sum;
        sum += v;
    }
    s[t] = sum; __syncthreads();
    for (int off = 1; off < 256; off <<= 1){
        int x = (t >= off) ? s[t - off] : 0;
        __syncthreads();
        s[t] += x;
        __syncthreads();
    }
    int base = (t > 0) ? s[t - 1] : 0;
    #pragma unroll
    for (int i = 0; i < PT; i++){
        int idx = t * PT + i;
        if (idx < NB) bbase[idx] = base + loc[i];
    }
    if (t == 255){
        bbase[NB] = s[255];      // == NE
        rowptr[NN] = s[255];
    }
}

// Per-bucket offsets: wave-per-bucket shfl scan over the 128 per-block counts.
__global__ __launch_bounds__(256) void k_boffset(const int* __restrict__ bbase, int* __restrict__ bh){
    int k = blockIdx.x * 4 + (threadIdx.x >> 6);
    int lane = threadIdx.x & 63;
    if (k >= NB) return;
    int v0 = bh[k * NBLK + 2 * lane];
    int v1 = bh[k * NBLK + 2 * lane + 1];
    int s = v0 + v1;
    #pragma unroll
    for (int off = 1; off < 64; off <<= 1){
        int x = __shfl_up(s, off);
        if (lane >= off) s += x;
    }
    int base = bbase[k] + s - (v0 + v1);   // exclusive prefix of pair sums
    bh[k * NBLK + 2 * lane]     = base;
    bh[k * NBLK + 2 * lane + 1] = base + v0;
}

__global__ __launch_bounds__(256) void k_bucket(const int* __restrict__ src, const int* __restrict__ dst,
                                                const int* __restrict__ bh, unsigned* __restrict__ bpairs){
    __shared__ int cur[NB];
    const int t = threadIdx.x, b = blockIdx.x;
    for (int k = t; k < NB; k += 256) cur[k] = bh[k * NBLK + b];
    __syncthreads();
    const int beg = b * CH, end = (beg + CH < NE) ? beg + CH : NE;
    for (int i = beg + t; i < end; i += 256){
        int s = src[i];
        int d = dst[i];
        if ((unsigned)s >= NN) s = 0;
        if ((unsigned)d >= NN) d = 0;
        int p = atomicAdd(&cur[d >> 6], 1);
        if ((unsigned)p < NE) bpairs[p] = (unsigned)s | ((unsigned)(d & 63) << 16);
    }
}

__global__ __launch_bounds__(256) void k_bsort(const unsigned* __restrict__ bpairs, const int* __restrict__ bbase,
                                               int* __restrict__ rowptr, int* __restrict__ csrsrc){
    __shared__ int cnt[64];
    __shared__ int cur[64];
    const int t = threadIdx.x;
    const int b = blockIdx.x;
    const int base = bbase[b];
    const int endb = bbase[b + 1];
    if (t < 64) cnt[t] = 0;
    __syncthreads();
    for (int i = base + t; i < endb; i += 256)
        atomicAdd(&cnt[bpairs[i] >> 16], 1);
    __syncthreads();
    if (t < 64){   // wave 0 exactly: 64-lane exclusive scan via shfl
        int v = cnt[t];
        int inc = v;
        #pragma unroll
        for (int off = 1; off < 64; off <<= 1){
            int x = __shfl_up(inc, off);
            if (t >= off) inc += x;
        }
        int excl = inc - v;
        cur[t] = excl;
        int d = b * 64 + t;
        if (d < NN) rowptr[d] = base + excl;
    }
    __syncthreads();
    for (int i = base + t; i < endb; i += 256){
        unsigned pr = bpairs[i];
        int p = atomicAdd(&cur[pr >> 16], 1);
        csrsrc[base + p] = (int)(pr & 0xFFFFu);
    }
}

// ---------------- MFMA GEMM (layers 1-2): ft = X @ W, bf16 in / f32 acc / bf16 out ----------------

#define XPAD 136   // 17*8: keeps 16B alignment, breaks bank stride

template<bool XDYN>
__global__ __launch_bounds__(256) void k_mgemm(const void* __restrict__ X, const unsigned short* __restrict__ wtg,
                                               const void* __restrict__ al, const void* __restrict__ ar,
                                               const int* __restrict__ dflag, bf16* __restrict__ ft,
                                               float* __restrict__ el, float* __restrict__ er){
    __shared__ unsigned short xs[64 * XPAD];
    __shared__ unsigned short wt[128 * XPAD];
    const int isbf = *dflag;
    const int t  = threadIdx.x;
    const int n0 = blockIdx.x * 64;

    for (int i2 = t; i2 < 8192; i2 += 256){
        unsigned v = ((const unsigned*)wtg)[i2];
        int r = i2 >> 6, c2 = (i2 & 63) * 2;
        *(unsigned*)&wt[r * XPAD + c2] = v;
    }
    for (int i2 = t; i2 < 4096; i2 += 256){
        int r = i2 >> 6, c2 = (i2 & 63) * 2;
        int n = n0 + r;
        float v0 = 0.f, v1 = 0.f;
        if (n < NN){
            if (XDYN){ v0 = ldf(X, n * FF + c2, isbf); v1 = ldf(X, n * FF + c2 + 1, isbf); }
            else     { v0 = ((const float*)X)[n * FF + c2]; v1 = ((const float*)X)[n * FF + c2 + 1]; }
        }
        unsigned pk = (unsigned)f2bfu(v0) | ((unsigned)f2bfu(v1) << 16);
        *(unsigned*)&xs[r * XPAD + c2] = pk;
    }
    __syncthreads();

    const int wv = t >> 6;
    const int lane = t & 63;
    const int quad = lane >> 4;
    const int mcol = lane & 15;

    bf16x8 afr[4];
    const unsigned short* xrow = &xs[(wv * 16 + mcol) * XPAD + quad * 8];
    #pragma unroll
    for (int kt = 0; kt < 4; kt++)
        afr[kt] = *(const bf16x8*)(xrow + kt * 32);

    float elp[4] = {0.f,0.f,0.f,0.f}, erp[4] = {0.f,0.f,0.f,0.f};

    #pragma unroll
    for (int f = 0; f < 8; f++){
        f32x4 acc = {0.f, 0.f, 0.f, 0.f};
        const unsigned short* wrow = &wt[(f * 16 + mcol) * XPAD + quad * 8];
        #pragma unroll
        for (int kt = 0; kt < 4; kt++){
            bf16x8 bfr = *(const bf16x8*)(wrow + kt * 32);
            acc = __builtin_amdgcn_mfma_f32_16x16x32_bf16(afr[kt], bfr, acc, 0, 0, 0);
        }
        int col = f * 16 + mcol;
        float alv = ldf(al, col, isbf);
        float arv = ldf(ar, col, isbf);
        #pragma unroll
        for (int reg = 0; reg < 4; reg++){
            int node = n0 + wv * 16 + quad * 4 + reg;
            float v = acc[reg];
            if (node < NN) ft[node * FF + col] = __float2bfloat16(v);
            elp[reg] += v * alv;
            erp[reg] += v * arv;
        }
    }

    #pragma unroll
    for (int reg = 0; reg < 4; reg++){
        float pl = elp[reg], pr = erp[reg];
        #pragma unroll
        for (int off = 1; off < 16; off <<= 1){
            pl += __shfl_xor(pl, off);
            pr += __shfl_xor(pr, off);
        }
        int node = n0 + wv * 16 + quad * 4 + reg;
        if (mcol == 0 && node < NN){ el[node] = pl; er[node] = pr; }
    }
}

// ---------------- layer-3 GEMM (vector, OUT=16, BN=16) + fused el/er ----------------

__global__ __launch_bounds__(256) void k_gemm3(const float* __restrict__ X, const void* __restrict__ W,
                                               const void* __restrict__ al, const void* __restrict__ ar,
                                               const int* __restrict__ dflag, float* __restrict__ ft,
                                               float* __restrict__ el, float* __restrict__ er){
    constexpr int BN = 16;
    __shared__ float xs[FF][BN + 1];
    const int isbf = *dflag;
    const int t  = threadIdx.x;
    const int n0 = blockIdx.x * BN;

    for (int idx = t; idx < BN * FF; idx += 256){
        int r = idx >> 7;
        int c = idx & 127;
        int n = n0 + r;
        xs[c][r] = (n < NN) ? X[n * FF + c] : 0.f;
    }
    __syncthreads();

    const int tx = t & 15;    // output feature
    const int rg = t >> 4;    // node
    float acc = 0.f;
    if (isbf){
        const bf16* Wb = (const bf16*)W;
        for (int k = 0; k < FF; k++)
            acc += __bfloat162float(Wb[k * CC + tx]) * xs[k][rg];
    } else {
        const float* Wf = (const float*)W;
        for (int k = 0; k < FF; k++)
            acc += Wf[k * CC + tx] * xs[k][rg];
    }

    int n = n0 + rg;
    if (n < NN) ft[n * CC + tx] = acc;

    float alv = ldf(al, tx, isbf);
    float arv = ldf(ar, tx, isbf);
    float pl = acc * alv, pr = acc * arv;
    #pragma unroll
    for (int off = 1; off < 16; off <<= 1){
        pl += __shfl_xor(pl, off);
        pr += __shfl_xor(pr, off);
    }
    if (tx == 0 && n < NN){ el[n] = pl; er[n] = pr; }
}

// ---------------- Aggregation (128 feats, bf16 ft): 16-lane edge groups ----------------
// Pass 2: chunks of 4 batches (16 edges), ALL array indices compile-time static
// (dynamic indices send private arrays to LDS — round-11 regression). Prefetch of
// chunk c+1 overlaps consumption of chunk c; wave-uniform guard, zero-fill tail.

__global__ __launch_bounds__(256) void k_agg128(const void* __restrict__ ftv, const float* __restrict__ el,
                                                const float* __restrict__ er, const int* __restrict__ rowptr,
                                                const int* __restrict__ csrsrc, const void* __restrict__ bias,
                                                const int* __restrict__ dflag, float* __restrict__ outp){
    const int isbf = *dflag;
    int lane = threadIdx.x & 63;
    int n = blockIdx.x * 4 + (threadIdx.x >> 6);
    if (n >= NN) return;
    int beg = rowptr[n], end = rowptr[n + 1];
    beg = (beg < 0) ? 0 : (beg > NE ? NE : beg);
    end = (end < beg) ? beg : (end > NE ? NE : end);
    int deg = end - beg;
    float erd = er[n];

    // Pass 1
    float m = -3.4e38f;
    int   s_c = 0;
    float e_c = 0.f;
    for (int i = beg + lane; i < end; i += 64){
        int s = csrsrc[i];
        if ((unsigned)s >= NN) s = 0;
        float e = el[s] + erd;
        e = (e >= 0.f) ? e : 0.2f * e;
        if (i < beg + 64){ s_c = s; e_c = e; }
        m = fmaxf(m, e);
    }
    #pragma unroll
    for (int off = 32; off; off >>= 1) m = fmaxf(m, __shfl_xor(m, off));

    int jmax = (deg < 64) ? deg : 64;
    float w_c = (lane < jmax) ? __expf(e_c - m) : 0.f;
    float lsum = w_c;
    #pragma unroll
    for (int off = 32; off; off >>= 1) lsum += __shfl_xor(lsum, off);

    // Pass 2: 16-lane groups; group g handles edge 4b+g of batch b.
    const uint4* ftq = (const uint4*)ftv;     // row n at ftq[n*16 + fl]
    const int g  = lane >> 4;
    const int fl = lane & 15;
    float a8[8];
    #pragma unroll
    for (int i = 0; i < 8; i++) a8[i] = 0.f;

    int nbatch = (jmax + 3) >> 2;     // 0..16 batches of 4 edges
    int nchunk = (nbatch + 3) >> 2;   // 0..4 chunks of 4 batches

    if (nchunk > 0){
        float wqa[4]; uint4 uqa[4];
        #pragma unroll
        for (int q = 0; q < 4; q++){
            int eidx = (q * 4 + g) & 63;
            int s = __shfl(s_c, eidx);
            wqa[q] = (q < nbatch) ? __shfl(w_c, eidx) : 0.f;
            uqa[q] = ftq[(unsigned)s * 16 + fl];
        }
        for (int c = 0; c < nchunk; c++){
            float wqb[4]; uint4 uqb[4];
            if (c + 1 < nchunk){
                #pragma unroll
                for (int q = 0; q < 4; q++){
                    int b = (c + 1) * 4 + q;
                    int eidx = (b * 4 + g) & 63;
                    int s = __shfl(s_c, eidx);
                    wqb[q] = (b < nbatch) ? __shfl(w_c, eidx) : 0.f;
                    uqb[q] = ftq[(unsigned)s * 16 + fl];
                }
            } else {
                #pragma unroll
                for (int q = 0; q < 4; q++){
                    wqb[q] = 0.f;
                    uqb[q].x = 0u; uqb[q].y = 0u; uqb[q].z = 0u; uqb[q].w = 0u;
                }
            }
            #pragma unroll
            for (int q = 0; q < 4; q++){
                float w = wqa[q]; uint4 u = uqa[q];
                a8[0] += w * bflo(u.x); a8[1] += w * bfhi(u.x);
                a8[2] += w * bflo(u.y); a8[3] += w * bfhi(u.y);
                a8[4] += w * bflo(u.z); a8[5] += w * bfhi(u.z);
                a8[6] += w * bflo(u.w); a8[7] += w * bfhi(u.w);
            }
            #pragma unroll
            for (int q = 0; q < 4; q++){ wqa[q] = wqb[q]; uqa[q] = uqb[q]; }
        }
    }

    // Rare tail (deg > 64): wave-uniform; only group 0 accumulates features.
    for (int i = beg + 64; i < end; ++i){
        int s = csrsrc[i];
        if ((unsigned)s >= NN) s = 0;
        float e = el[s] + erd;
        e = (e >= 0.f) ? e : 0.2f * e;
        float w = __expf(e - m);
        lsum += w;
        if (g == 0){
            uint4 u = ftq[(unsigned)s * 16 + fl];
            a8[0] += w * bflo(u.x); a8[1] += w * bfhi(u.x);
            a8[2] += w * bflo(u.y); a8[3] += w * bfhi(u.y);
            a8[4] += w * bflo(u.z); a8[5] += w * bfhi(u.z);
            a8[6] += w * bflo(u.w); a8[7] += w * bfhi(u.w);
        }
    }

    // Combine the 4 edge groups.
    #pragma unroll
    for (int i = 0; i < 8; i++){
        a8[i] += __shfl_xor(a8[i], 16);
        a8[i] += __shfl_xor(a8[i], 32);
    }
    float inv = 1.f / ((lsum > 0.f) ? lsum : 1.f);
    if (lane < 16){
        float4 o0, o1;
        o0.x = fmaxf(a8[0] * inv + ldf(bias, fl * 8 + 0, isbf), 0.f);
        o0.y = fmaxf(a8[1] * inv + ldf(bias, fl * 8 + 1, isbf), 0.f);
        o0.z = fmaxf(a8[2] * inv + ldf(bias, fl * 8 + 2, isbf), 0.f);
        o0.w = fmaxf(a8[3] * inv + ldf(bias, fl * 8 + 3, isbf), 0.f);
        o1.x = fmaxf(a8[4] * inv + ldf(bias, fl * 8 + 4, isbf), 0.f);
        o1.y = fmaxf(a8[5] * inv + ldf(bias, fl * 8 + 5, isbf), 0.f);
        o1.z = fmaxf(a8[6] * inv + ldf(bias, fl * 8 + 6, isbf), 0.f);
        o1.w = fmaxf(a8[7] * inv + ldf(bias, fl * 8 + 7, isbf), 0.f);
        ((float4*)outp)[n * 32 + fl * 2]     = o0;
        ((float4*)outp)[n * 32 + fl * 2 + 1] = o1;
    }
}

// ---------------- Aggregation (16 feats, f32 ft): 4-lane edge groups, final output ----------------

__global__ __launch_bounds__(256) void k_agg16(const float* __restrict__ ftv, const float* __restrict__ el,
                                               const float* __restrict__ er, const int* __restrict__ rowptr,
                                               const int* __restrict__ csrsrc, const void* __restrict__ bias,
                                               const int* __restrict__ dflag, void* __restrict__ outp){
    const int isbf = *dflag;
    int lane = threadIdx.x & 63;
    int n = blockIdx.x * 4 + (threadIdx.x >> 6);
    if (n >= NN) return;
    int beg = rowptr[n], end = rowptr[n + 1];
    beg = (beg < 0) ? 0 : (beg > NE ? NE : beg);
    end = (end < beg) ? beg : (end > NE ? NE : end);
    int deg = end - beg;
    float erd = er[n];

    float m = -3.4e38f;
    int   s_c = 0;
    float e_c = 0.f;
    for (int i = beg + lane; i < end; i += 64){
        int s = csrsrc[i];
        if ((unsigned)s >= NN) s = 0;
        float e = el[s] + erd;
        e = (e >= 0.f) ? e : 0.2f * e;
        if (i < beg + 64){ s_c = s; e_c = e; }
        m = fmaxf(m, e);
    }
    #pragma unroll
    for (int off = 32; off; off >>= 1) m = fmaxf(m, __shfl_xor(m, off));

    int jmax = (deg < 64) ? deg : 64;
    float w_c = (lane < jmax) ? __expf(e_c - m) : 0.f;
    float lsum = w_c;
    #pragma unroll
    for (int off = 32; off; off >>= 1) lsum += __shfl_xor(lsum, off);

    // 4-lane groups: 16 edges per batch, <=4 batches. Row = 4 lanes x float4.
    const float4* ftq = (const float4*)ftv;   // row n at ftq[n*4 + fl2]
    const int g   = lane >> 2;    // edge-in-batch 0..15
    const int fl2 = lane & 3;
    int nbatch = (jmax + 15) >> 4;    // <= 4
    float wq[4]; float4 uq[4];
    #pragma unroll
    for (int q = 0; q < 4; q++){
        int eidx = (q * 16 + g) & 63;
        int s = __shfl(s_c, eidx);
        wq[q] = (q < nbatch) ? __shfl(w_c, eidx) : 0.f;
        uq[q] = ftq[(unsigned)s * 4 + fl2];
    }
    float a4[4] = {0.f,0.f,0.f,0.f};
    #pragma unroll
    for (int q = 0; q < 4; q++){
        a4[0] += wq[q] * uq[q].x;
        a4[1] += wq[q] * uq[q].y;
        a4[2] += wq[q] * uq[q].z;
        a4[3] += wq[q] * uq[q].w;
    }
    // Rare tail (deg > 64): only group 0 accumulates.
    for (int i = beg + 64; i < end; ++i){
        int s = csrsrc[i];
        if ((unsigned)s >= NN) s = 0;
        float e = el[s] + erd;
        e = (e >= 0.f) ? e : 0.2f * e;
        float w = __expf(e - m);
        lsum += w;
        if (g == 0){
            float4 u = ftq[(unsigned)s * 4 + fl2];
            a4[0] += w * u.x; a4[1] += w * u.y; a4[2] += w * u.z; a4[3] += w * u.w;
        }
    }
    #pragma unroll
    for (int i = 0; i < 4; i++){
        a4[i] += __shfl_xor(a4[i], 4);
        a4[i] += __shfl_xor(a4[i], 8);
        a4[i] += __shfl_xor(a4[i], 16);
        a4[i] += __shfl_xor(a4[i], 32);
    }
    float inv = 1.f / ((lsum > 0.f) ? lsum : 1.f);
    if (lane < 4){
        float o0 = fmaxf(a4[0] * inv + ldf(bias, fl2 * 4 + 0, isbf), 0.f);
        float o1 = fmaxf(a4[1] * inv + ldf(bias, fl2 * 4 + 1, isbf), 0.f);
        float o2 = fmaxf(a4[2] * inv + ldf(bias, fl2 * 4 + 2, isbf), 0.f);
        float o3 = fmaxf(a4[3] * inv + ldf(bias, fl2 * 4 + 3, isbf), 0.f);
        if (isbf){
            uint2 pk;
            pk.x = (unsigned)f2bfu(o0) | ((unsigned)f2bfu(o1) << 16);
            pk.y = (unsigned)f2bfu(o2) | ((unsigned)f2bfu(o3) << 16);
            ((uint2*)outp)[n * 4 + fl2] = pk;
        } else {
            float4 o; o.x = o0; o.y = o1; o.z = o2; o.w = o3;
            ((float4*)outp)[n * 4 + fl2] = o;
        }
    }
}

// ---------------- host launch ----------------

static size_t align256(size_t x){ return (x + 255) & ~(size_t)255; }

extern "C" void kernel_launch(void* const* d_in, const int* in_sizes, int n_in,
                              void* d_out, int out_size, void* d_ws, size_t ws_size,
                              hipStream_t stream) {
    const void* feat = d_in[0];
    const int*  src  = (const int*)d_in[1];
    const int*  dst  = (const int*)d_in[2];
    const void* W1 = d_in[3];
    const void* al1= d_in[4];
    const void* ar1= d_in[5];
    const void* b1 = d_in[6];
    const void* W2 = d_in[7];
    const void* al2= d_in[8];
    const void* ar2= d_in[9];
    const void* b2 = d_in[10];
    const void* W3 = d_in[11];
    const void* al3= d_in[12];
    const void* ar3= d_in[13];
    const void* b3 = d_in[14];

    // workspace carve
    char* p = (char*)d_ws;
    size_t off = 0;
    auto carve = [&](size_t bytes)->void*{
        void* r = p + off;
        off += align256(bytes);
        return r;
    };
    float* ftA   = (float*)carve((size_t)NN * FF * 4);   // ft buffer: bf16 view (layers 1/2), f32 view (layer 3)
    float* hB    = (float*)carve((size_t)NN * FF * 4);   // hidden state; bpairs overlays it pre-layer-1
    float* el    = (float*)carve((size_t)NN * 4);
    float* er    = (float*)carve((size_t)NN * 4);
    int*   rowptr= (int*)  carve((size_t)(NN + 1) * 4);
    int*   csrsrc= (int*)  carve((size_t)NE * 4);
    int*   bcounts=(int*)  carve((size_t)NB * 4);
    int*   bbase  =(int*)  carve((size_t)(NB + 1) * 4);
    int*   bh     =(int*)  carve((size_t)NB * NBLK * 4);  // per-(bucket,block) hist/offsets, 400KB
    unsigned short* wtg = (unsigned short*)carve(2 * 16384 * 2);  // W1t,W2t bf16 [feat][k]
    int*   dflag  =(int*)  carve(256);
    unsigned* bpairs = (unsigned*)hB;   // overlay: consumed before hB is first written
    void*  ftb   = ftA;                 // bf16 ft view (layers 1-2); f32 ft3 view (layer 3)
    (void)ws_size; (void)n_in; (void)in_sizes; (void)out_size;

    dim3 b256(256);

    k_detect<<<dim3(1), b256, 0, stream>>>((const unsigned short*)feat, dflag);
    k_wprep<<<dim3(128), b256, 0, stream>>>(W1, W2, dflag, wtg);

    // CSR build via hierarchical counting sort
    k_zero<<<dim3((NB + 255) / 256), b256, 0, stream>>>(bcounts, NB);
    k_bcount<<<dim3(NBLK), b256, 0, stream>>>(dst, bcounts, bh);
    k_bscan<<<dim3(1), b256, 0, stream>>>(bcounts, bbase, rowptr);
    k_boffset<<<dim3((NB + 3) / 4), b256, 0, stream>>>(bbase, bh);
    k_bucket<<<dim3(NBLK), b256, 0, stream>>>(src, dst, bh, bpairs);
    k_bsort<<<dim3(NB), b256, 0, stream>>>(bpairs, bbase, rowptr, csrsrc);

    const int mg_grid   = (NN + 63) / 64;     // 782
    const int g3_grid   = (NN + 15) / 16;     // 3125
    const int node_grid = (NN + 3) / 4;       // 12500

    // Layer 1
    k_mgemm<true><<<dim3(mg_grid), b256, 0, stream>>>(feat, wtg, al1, ar1, dflag, (bf16*)ftb, el, er);
    k_agg128<<<dim3(node_grid), b256, 0, stream>>>(ftb, el, er, rowptr, csrsrc, b1, dflag, hB);

    // Layer 2
    k_mgemm<false><<<dim3(mg_grid), b256, 0, stream>>>(hB, wtg + 16384, al2, ar2, dflag, (bf16*)ftb, el, er);
    k_agg128<<<dim3(node_grid), b256, 0, stream>>>(ftb, el, er, rowptr, csrsrc, b2, dflag, hB);

    // Layer 3
    k_gemm3<<<dim3(g3_grid), b256, 0, stream>>>(hB, W3, al3, ar3, dflag, (float*)ftb, el, er);
    k_agg16<<<dim3(node_grid), b256, 0, stream>>>((const float*)ftb, el, er, rowptr, csrsrc, b3, dflag, d_out);
}

// Round 13
// 366.837 us; speedup vs baseline: 1.3611x; 1.0800x over previous
//
#include <hip/hip_runtime.h>
#include <hip/hip_bf16.h>

#define NN 50000
#define NE 1600000
#define FF 128
#define CC 16
#define NB ((NN + 63) / 64)       // 782 dst-buckets of 64 nodes
#define NBLK 128                  // partition blocks for the sort
#define CH ((NE + NBLK - 1) / NBLK)   // 12500 edges per partition block

using bf16 = __hip_bfloat16;
using bf16x8 = __attribute__((ext_vector_type(8))) short;   // 8 bf16 = 4 VGPRs
using f32x4  = __attribute__((ext_vector_type(4))) float;

// Runtime-dtype load: isbf selects bf16 vs f32 interpretation of p.
static __device__ __forceinline__ float ldf(const void* p, int i, int isbf){
    return isbf ? __bfloat162float(((const bf16*)p)[i]) : ((const float*)p)[i];
}
static __device__ __forceinline__ float bflo(unsigned u){
    union{unsigned x; float f;} c; c.x = u << 16; return c.f;
}
static __device__ __forceinline__ float bfhi(unsigned u){
    union{unsigned x; float f;} c; c.x = u & 0xFFFF0000u; return c.f;
}
static __device__ __forceinline__ float rdlanef(float v, int l){
    return __int_as_float(__builtin_amdgcn_readlane(__float_as_int(v), l));
}
static __device__ __forceinline__ unsigned short f2bfu(float v){
    bf16 b = __float2bfloat16(v);
    union{bf16 b; unsigned short u;} c; c.b = b; return c.u;
}

// ---------------- dtype detector ----------------
__global__ __launch_bounds__(256) void k_detect(const unsigned short* __restrict__ u,
                                                int* __restrict__ flag){
    int t = threadIdx.x;
    unsigned short lo = u[2 * t];
    int e = (lo >> 7) & 0xFF;
    int sane = (e >= 117 && e <= 137) ? 1 : 0;
    __shared__ int cnt;
    if (t == 0) cnt = 0;
    __syncthreads();
    atomicAdd(&cnt, sane);
    __syncthreads();
    if (t == 0) *flag = (cnt >= 128) ? 1 : 0;   // 1 => bf16 data
}

__global__ __launch_bounds__(256) void k_zero(int* __restrict__ p, int n){
    int i = blockIdx.x * 256 + threadIdx.x;
    if (i < n) p[i] = 0;
}

// ---------------- W prep: Wt[feat][k] = bf16(W[k][feat]) for W1, W2 ----------------
__global__ __launch_bounds__(256) void k_wprep(const void* __restrict__ W1, const void* __restrict__ W2,
                                               const int* __restrict__ dflag, unsigned short* __restrict__ wtg){
    const int isbf = *dflag;
    int idx = blockIdx.x * 256 + threadIdx.x;   // 0 .. 32767
    int l = idx >> 14;                          // 0: W1, 1: W2
    int e = idx & 16383;
    int f = e >> 7, k = e & 127;
    const void* W = l ? W2 : W1;
    wtg[idx] = f2bfu(ldf(W, k * FF + f, isbf));
}

// ---------------- CSR build: hierarchical counting sort by dst ----------------

__global__ __launch_bounds__(256) void k_bcount(const int* __restrict__ dst, int* __restrict__ bcounts,
                                                int* __restrict__ bh){
    __shared__ int hist[NB];
    const int t = threadIdx.x, b = blockIdx.x;
    for (int i = t; i < NB; i += 256) hist[i] = 0;
    __syncthreads();
    const int beg = b * CH, end = (beg + CH < NE) ? beg + CH : NE;
    for (int i = beg + t; i < end; i += 256){
        int d = dst[i];
        if ((unsigned)d >= NN) d = 0;
        atomicAdd(&hist[d >> 6], 1);
    }
    __syncthreads();
    for (int k = t; k < NB; k += 256){
        int v = hist[k];
        bh[k * NBLK + b] = v;
        if (v) atomicAdd(&bcounts[k], v);
    }
}

__global__ __launch_bounds__(256) void k_bscan(const int* __restrict__ bcounts, int* __restrict__ bbase,
                                               int* __restrict__ rowptr){
    __shared__ int s[256];
    const int t = threadIdx.x;
    constexpr int PT = (NB + 255) / 256;   // 4
    int loc[PT];
    int sum = 0;
    #pragma unroll
    for (int i = 0; i < PT; i++){
        int idx = t * PT + i;
        int v = (idx < NB) ? bcounts[idx] : 0;
        loc[i] = sum;
        sum += v;
    }
    s[t] = sum; __syncthreads();
    for (int off = 1; off < 256; off <<= 1){
        int x = (t >= off) ? s[t - off] : 0;
        __syncthreads();
        s[t] += x;
        __syncthreads();
    }
    int base = (t > 0) ? s[t - 1] : 0;
    #pragma unroll
    for (int i = 0; i < PT; i++){
        int idx = t * PT + i;
        if (idx < NB) bbase[idx] = base + loc[i];
    }
    if (t == 255){
        bbase[NB] = s[255];      // == NE
        rowptr[NN] = s[255];
    }
}

// Per-bucket offsets: wave-per-bucket shfl scan over the 128 per-block counts.
__global__ __launch_bounds__(256) void k_boffset(const int* __restrict__ bbase, int* __restrict__ bh){
    int k = blockIdx.x * 4 + (threadIdx.x >> 6);
    int lane = threadIdx.x & 63;
    if (k >= NB) return;
    int v0 = bh[k * NBLK + 2 * lane];
    int v1 = bh[k * NBLK + 2 * lane + 1];
    int s = v0 + v1;
    #pragma unroll
    for (int off = 1; off < 64; off <<= 1){
        int x = __shfl_up(s, off);
        if (lane >= off) s += x;
    }
    int base = bbase[k] + s - (v0 + v1);   // exclusive prefix of pair sums
    bh[k * NBLK + 2 * lane]     = base;
    bh[k * NBLK + 2 * lane + 1] = base + v0;
}

__global__ __launch_bounds__(256) void k_bucket(const int* __restrict__ src, const int* __restrict__ dst,
                                                const int* __restrict__ bh, unsigned* __restrict__ bpairs){
    __shared__ int cur[NB];
    const int t = threadIdx.x, b = blockIdx.x;
    for (int k = t; k < NB; k += 256) cur[k] = bh[k * NBLK + b];
    __syncthreads();
    const int beg = b * CH, end = (beg + CH < NE) ? beg + CH : NE;
    for (int i = beg + t; i < end; i += 256){
        int s = src[i];
        int d = dst[i];
        if ((unsigned)s >= NN) s = 0;
        if ((unsigned)d >= NN) d = 0;
        int p = atomicAdd(&cur[d >> 6], 1);
        if ((unsigned)p < NE) bpairs[p] = (unsigned)s | ((unsigned)(d & 63) << 16);
    }
}

__global__ __launch_bounds__(256) void k_bsort(const unsigned* __restrict__ bpairs, const int* __restrict__ bbase,
                                               int* __restrict__ rowptr, int* __restrict__ csrsrc){
    __shared__ int cnt[64];
    __shared__ int cur[64];
    const int t = threadIdx.x;
    const int b = blockIdx.x;
    const int base = bbase[b];
    const int endb = bbase[b + 1];
    if (t < 64) cnt[t] = 0;
    __syncthreads();
    for (int i = base + t; i < endb; i += 256)
        atomicAdd(&cnt[bpairs[i] >> 16], 1);
    __syncthreads();
    if (t < 64){   // wave 0 exactly: 64-lane exclusive scan via shfl
        int v = cnt[t];
        int inc = v;
        #pragma unroll
        for (int off = 1; off < 64; off <<= 1){
            int x = __shfl_up(inc, off);
            if (t >= off) inc += x;
        }
        int excl = inc - v;
        cur[t] = excl;
        int d = b * 64 + t;
        if (d < NN) rowptr[d] = base + excl;
    }
    __syncthreads();
    for (int i = base + t; i < endb; i += 256){
        unsigned pr = bpairs[i];
        int p = atomicAdd(&cur[pr >> 16], 1);
        csrsrc[base + p] = (int)(pr & 0xFFFFu);
    }
}

// ---------------- MFMA GEMM (layers 1-2): ft = X @ W, bf16 in / f32 acc / bf16 out ----------------

#define XPAD 136   // 17*8: keeps 16B alignment, breaks bank stride

template<bool XDYN>
__global__ __launch_bounds__(256) void k_mgemm(const void* __restrict__ X, const unsigned short* __restrict__ wtg,
                                               const void* __restrict__ al, const void* __restrict__ ar,
                                               const int* __restrict__ dflag, bf16* __restrict__ ft,
                                               float* __restrict__ el, float* __restrict__ er){
    __shared__ unsigned short xs[64 * XPAD];
    __shared__ unsigned short wt[128 * XPAD];
    const int isbf = *dflag;
    const int t  = threadIdx.x;
    const int n0 = blockIdx.x * 64;

    for (int i2 = t; i2 < 8192; i2 += 256){
        unsigned v = ((const unsigned*)wtg)[i2];
        int r = i2 >> 6, c2 = (i2 & 63) * 2;
        *(unsigned*)&wt[r * XPAD + c2] = v;
    }
    for (int i2 = t; i2 < 4096; i2 += 256){
        int r = i2 >> 6, c2 = (i2 & 63) * 2;
        int n = n0 + r;
        float v0 = 0.f, v1 = 0.f;
        if (n < NN){
            if (XDYN){ v0 = ldf(X, n * FF + c2, isbf); v1 = ldf(X, n * FF + c2 + 1, isbf); }
            else     { v0 = ((const float*)X)[n * FF + c2]; v1 = ((const float*)X)[n * FF + c2 + 1]; }
        }
        unsigned pk = (unsigned)f2bfu(v0) | ((unsigned)f2bfu(v1) << 16);
        *(unsigned*)&xs[r * XPAD + c2] = pk;
    }
    __syncthreads();

    const int wv = t >> 6;
    const int lane = t & 63;
    const int quad = lane >> 4;
    const int mcol = lane & 15;

    bf16x8 afr[4];
    const unsigned short* xrow = &xs[(wv * 16 + mcol) * XPAD + quad * 8];
    #pragma unroll
    for (int kt = 0; kt < 4; kt++)
        afr[kt] = *(const bf16x8*)(xrow + kt * 32);

    float elp[4] = {0.f,0.f,0.f,0.f}, erp[4] = {0.f,0.f,0.f,0.f};

    #pragma unroll
    for (int f = 0; f < 8; f++){
        f32x4 acc = {0.f, 0.f, 0.f, 0.f};
        const unsigned short* wrow = &wt[(f * 16 + mcol) * XPAD + quad * 8];
        #pragma unroll
        for (int kt = 0; kt < 4; kt++){
            bf16x8 bfr = *(const bf16x8*)(wrow + kt * 32);
            acc = __builtin_amdgcn_mfma_f32_16x16x32_bf16(afr[kt], bfr, acc, 0, 0, 0);
        }
        int col = f * 16 + mcol;
        float alv = ldf(al, col, isbf);
        float arv = ldf(ar, col, isbf);
        #pragma unroll
        for (int reg = 0; reg < 4; reg++){
            int node = n0 + wv * 16 + quad * 4 + reg;
            float v = acc[reg];
            if (node < NN) ft[node * FF + col] = __float2bfloat16(v);
            elp[reg] += v * alv;
            erp[reg] += v * arv;
        }
    }

    #pragma unroll
    for (int reg = 0; reg < 4; reg++){
        float pl = elp[reg], pr = erp[reg];
        #pragma unroll
        for (int off = 1; off < 16; off <<= 1){
            pl += __shfl_xor(pl, off);
            pr += __shfl_xor(pr, off);
        }
        int node = n0 + wv * 16 + quad * 4 + reg;
        if (mcol == 0 && node < NN){ el[node] = pl; er[node] = pr; }
    }
}

// ---------------- layer-3 GEMM (vector, OUT=16, BN=16) + fused el/er ----------------

__global__ __launch_bounds__(256) void k_gemm3(const float* __restrict__ X, const void* __restrict__ W,
                                               const void* __restrict__ al, const void* __restrict__ ar,
                                               const int* __restrict__ dflag, float* __restrict__ ft,
                                               float* __restrict__ el, float* __restrict__ er){
    constexpr int BN = 16;
    __shared__ float xs[FF][BN + 1];
    const int isbf = *dflag;
    const int t  = threadIdx.x;
    const int n0 = blockIdx.x * BN;

    for (int idx = t; idx < BN * FF; idx += 256){
        int r = idx >> 7;
        int c = idx & 127;
        int n = n0 + r;
        xs[c][r] = (n < NN) ? X[n * FF + c] : 0.f;
    }
    __syncthreads();

    const int tx = t & 15;    // output feature
    const int rg = t >> 4;    // node
    float acc = 0.f;
    if (isbf){
        const bf16* Wb = (const bf16*)W;
        for (int k = 0; k < FF; k++)
            acc += __bfloat162float(Wb[k * CC + tx]) * xs[k][rg];
    } else {
        const float* Wf = (const float*)W;
        for (int k = 0; k < FF; k++)
            acc += Wf[k * CC + tx] * xs[k][rg];
    }

    int n = n0 + rg;
    if (n < NN) ft[n * CC + tx] = acc;

    float alv = ldf(al, tx, isbf);
    float arv = ldf(ar, tx, isbf);
    float pl = acc * alv, pr = acc * arv;
    #pragma unroll
    for (int off = 1; off < 16; off <<= 1){
        pl += __shfl_xor(pl, off);
        pr += __shfl_xor(pr, off);
    }
    if (tx == 0 && n < NN){ el[n] = pl; er[n] = pr; }
}

// ---------------- Aggregation (128 feats, bf16 ft): round-9 proven kernel ----------------
// One wave per dst node. Pass 1: parallel logits/max/weights/lsum. Pass 2:
// 8-deep software-pipelined dword gather (readlane src + weight, SGPR-base
// addressing); next batch's loads issue before current batch is consumed.

__global__ __launch_bounds__(256) void k_agg128(const void* __restrict__ ftv, const float* __restrict__ el,
                                                const float* __restrict__ er, const int* __restrict__ rowptr,
                                                const int* __restrict__ csrsrc, const void* __restrict__ bias,
                                                const int* __restrict__ dflag, float* __restrict__ outp){
    const int isbf = *dflag;
    int lane = threadIdx.x & 63;
    int n = blockIdx.x * 4 + (threadIdx.x >> 6);
    if (n >= NN) return;
    int beg = rowptr[n], end = rowptr[n + 1];
    beg = (beg < 0) ? 0 : (beg > NE ? NE : beg);
    end = (end < beg) ? beg : (end > NE ? NE : end);
    int deg = end - beg;
    float erd = er[n];

    // Pass 1: parallel logits + max; cache first 64 (src, logit) in registers.
    float m = -3.4e38f;
    int   s_c = 0;
    float e_c = 0.f;
    for (int i = beg + lane; i < end; i += 64){
        int s = csrsrc[i];
        if ((unsigned)s >= NN) s = 0;
        float e = el[s] + erd;
        e = (e >= 0.f) ? e : 0.2f * e;
        if (i < beg + 64){ s_c = s; e_c = e; }
        m = fmaxf(m, e);
    }
    #pragma unroll
    for (int off = 32; off; off >>= 1) m = fmaxf(m, __shfl_xor(m, off));

    int jmax = (deg < 64) ? deg : 64;
    float w_c = (lane < jmax) ? __expf(e_c - m) : 0.f;
    float lsum = w_c;
    #pragma unroll
    for (int off = 32; off; off >>= 1) lsum += __shfl_xor(lsum, off);

    const unsigned* ftb = (const unsigned*)ftv;
    float acc0 = 0.f, acc1 = 0.f;
    int j = 0;
    if (jmax >= 8){
        float w[8]; unsigned u[8];
        #pragma unroll
        for (int q = 0; q < 8; q++){
            int s = __builtin_amdgcn_readlane(s_c, q);
            w[q] = rdlanef(w_c, q);
            u[q] = (ftb + s * 64)[lane];
        }
        for (j = 8; j + 8 <= jmax; j += 8){
            float wn[8]; unsigned un[8];
            #pragma unroll
            for (int q = 0; q < 8; q++){
                int s = __builtin_amdgcn_readlane(s_c, j + q);
                wn[q] = rdlanef(w_c, j + q);
                un[q] = (ftb + s * 64)[lane];
            }
            #pragma unroll
            for (int q = 0; q < 8; q++){
                acc0 += w[q] * bflo(u[q]);
                acc1 += w[q] * bfhi(u[q]);
                w[q] = wn[q]; u[q] = un[q];
            }
        }
        #pragma unroll
        for (int q = 0; q < 8; q++){
            acc0 += w[q] * bflo(u[q]);
            acc1 += w[q] * bfhi(u[q]);
        }
    }
    for (; j < jmax; ++j){
        int s = __builtin_amdgcn_readlane(s_c, j);
        float w = rdlanef(w_c, j);
        unsigned u = (ftb + s * 64)[lane];
        acc0 += w * bflo(u); acc1 += w * bfhi(u);
    }
    // Rare tail (deg > 64)
    for (int i = beg + 64; i < end; ++i){
        int s = csrsrc[i];
        if ((unsigned)s >= NN) s = 0;
        float e = el[s] + erd;
        e = (e >= 0.f) ? e : 0.2f * e;
        float w = __expf(e - m);
        unsigned u = (ftb + s * 64)[lane];
        lsum += w;
        acc0 += w * bflo(u); acc1 += w * bfhi(u);
    }
    float inv = 1.f / ((lsum > 0.f) ? lsum : 1.f);
    float2 o;
    o.x = fmaxf(acc0 * inv + ldf(bias, 2 * lane,     isbf), 0.f);
    o.y = fmaxf(acc1 * inv + ldf(bias, 2 * lane + 1, isbf), 0.f);
    ((float2*)outp)[n * 64 + lane] = o;
}

// ---------------- Aggregation (16 feats, f32 ft): 4-lane edge groups, final output ----------------

__global__ __launch_bounds__(256) void k_agg16(const float* __restrict__ ftv, const float* __restrict__ el,
                                               const float* __restrict__ er, const int* __restrict__ rowptr,
                                               const int* __restrict__ csrsrc, const void* __restrict__ bias,
                                               const int* __restrict__ dflag, void* __restrict__ outp){
    const int isbf = *dflag;
    int lane = threadIdx.x & 63;
    int n = blockIdx.x * 4 + (threadIdx.x >> 6);
    if (n >= NN) return;
    int beg = rowptr[n], end = rowptr[n + 1];
    beg = (beg < 0) ? 0 : (beg > NE ? NE : beg);
    end = (end < beg) ? beg : (end > NE ? NE : end);
    int deg = end - beg;
    float erd = er[n];

    float m = -3.4e38f;
    int   s_c = 0;
    float e_c = 0.f;
    for (int i = beg + lane; i < end; i += 64){
        int s = csrsrc[i];
        if ((unsigned)s >= NN) s = 0;
        float e = el[s] + erd;
        e = (e >= 0.f) ? e : 0.2f * e;
        if (i < beg + 64){ s_c = s; e_c = e; }
        m = fmaxf(m, e);
    }
    #pragma unroll
    for (int off = 32; off; off >>= 1) m = fmaxf(m, __shfl_xor(m, off));

    int jmax = (deg < 64) ? deg : 64;
    float w_c = (lane < jmax) ? __expf(e_c - m) : 0.f;
    float lsum = w_c;
    #pragma unroll
    for (int off = 32; off; off >>= 1) lsum += __shfl_xor(lsum, off);

    // 4-lane groups: 16 edges per batch, <=4 batches. Row = 4 lanes x float4.
    const float4* ftq = (const float4*)ftv;   // row n at ftq[n*4 + fl2]
    const int g   = lane >> 2;    // edge-in-batch 0..15
    const int fl2 = lane & 3;
    int nbatch = (jmax + 15) >> 4;    // <= 4
    float wq[4]; float4 uq[4];
    #pragma unroll
    for (int q = 0; q < 4; q++){
        int eidx = (q * 16 + g) & 63;
        int s = __shfl(s_c, eidx);
        wq[q] = (q < nbatch) ? __shfl(w_c, eidx) : 0.f;
        uq[q] = ftq[(unsigned)s * 4 + fl2];
    }
    float a4[4] = {0.f,0.f,0.f,0.f};
    #pragma unroll
    for (int q = 0; q < 4; q++){
        a4[0] += wq[q] * uq[q].x;
        a4[1] += wq[q] * uq[q].y;
        a4[2] += wq[q] * uq[q].z;
        a4[3] += wq[q] * uq[q].w;
    }
    // Rare tail (deg > 64): only group 0 accumulates.
    for (int i = beg + 64; i < end; ++i){
        int s = csrsrc[i];
        if ((unsigned)s >= NN) s = 0;
        float e = el[s] + erd;
        e = (e >= 0.f) ? e : 0.2f * e;
        float w = __expf(e - m);
        lsum += w;
        if (g == 0){
            float4 u = ftq[(unsigned)s * 4 + fl2];
            a4[0] += w * u.x; a4[1] += w * u.y; a4[2] += w * u.z; a4[3] += w * u.w;
        }
    }
    #pragma unroll
    for (int i = 0; i < 4; i++){
        a4[i] += __shfl_xor(a4[i], 4);
        a4[i] += __shfl_xor(a4[i], 8);
        a4[i] += __shfl_xor(a4[i], 16);
        a4[i] += __shfl_xor(a4[i], 32);
    }
    float inv = 1.f / ((lsum > 0.f) ? lsum : 1.f);
    if (lane < 4){
        float o0 = fmaxf(a4[0] * inv + ldf(bias, fl2 * 4 + 0, isbf), 0.f);
        float o1 = fmaxf(a4[1] * inv + ldf(bias, fl2 * 4 + 1, isbf), 0.f);
        float o2 = fmaxf(a4[2] * inv + ldf(bias, fl2 * 4 + 2, isbf), 0.f);
        float o3 = fmaxf(a4[3] * inv + ldf(bias, fl2 * 4 + 3, isbf), 0.f);
        if (isbf){
            uint2 pk;
            pk.x = (unsigned)f2bfu(o0) | ((unsigned)f2bfu(o1) << 16);
            pk.y = (unsigned)f2bfu(o2) | ((unsigned)f2bfu(o3) << 16);
            ((uint2*)outp)[n * 4 + fl2] = pk;
        } else {
            float4 o; o.x = o0; o.y = o1; o.z = o2; o.w = o3;
            ((float4*)outp)[n * 4 + fl2] = o;
        }
    }
}

// ---------------- host launch ----------------

static size_t align256(size_t x){ return (x + 255) & ~(size_t)255; }

extern "C" void kernel_launch(void* const* d_in, const int* in_sizes, int n_in,
                              void* d_out, int out_size, void* d_ws, size_t ws_size,
                              hipStream_t stream) {
    const void* feat = d_in[0];
    const int*  src  = (const int*)d_in[1];
    const int*  dst  = (const int*)d_in[2];
    const void* W1 = d_in[3];
    const void* al1= d_in[4];
    const void* ar1= d_in[5];
    const void* b1 = d_in[6];
    const void* W2 = d_in[7];
    const void* al2= d_in[8];
    const void* ar2= d_in[9];
    const void* b2 = d_in[10];
    const void* W3 = d_in[11];
    const void* al3= d_in[12];
    const void* ar3= d_in[13];
    const void* b3 = d_in[14];

    // workspace carve
    char* p = (char*)d_ws;
    size_t off = 0;
    auto carve = [&](size_t bytes)->void*{
        void* r = p + off;
        off += align256(bytes);
        return r;
    };
    float* ftA   = (float*)carve((size_t)NN * FF * 4);   // ft buffer: bf16 view (layers 1/2), f32 view (layer 3)
    float* hB    = (float*)carve((size_t)NN * FF * 4);   // hidden state; bpairs overlays it pre-layer-1
    float* el    = (float*)carve((size_t)NN * 4);
    float* er    = (float*)carve((size_t)NN * 4);
    int*   rowptr= (int*)  carve((size_t)(NN + 1) * 4);
    int*   csrsrc= (int*)  carve((size_t)NE * 4);
    int*   bcounts=(int*)  carve((size_t)NB * 4);
    int*   bbase  =(int*)  carve((size_t)(NB + 1) * 4);
    int*   bh     =(int*)  carve((size_t)NB * NBLK * 4);  // per-(bucket,block) hist/offsets, 400KB
    unsigned short* wtg = (unsigned short*)carve(2 * 16384 * 2);  // W1t,W2t bf16 [feat][k]
    int*   dflag  =(int*)  carve(256);
    unsigned* bpairs = (unsigned*)hB;   // overlay: consumed before hB is first written
    void*  ftb   = ftA;                 // bf16 ft view (layers 1-2); f32 ft3 view (layer 3)
    (void)ws_size; (void)n_in; (void)in_sizes; (void)out_size;

    dim3 b256(256);

    k_detect<<<dim3(1), b256, 0, stream>>>((const unsigned short*)feat, dflag);
    k_wprep<<<dim3(128), b256, 0, stream>>>(W1, W2, dflag, wtg);

    // CSR build via hierarchical counting sort
    k_zero<<<dim3((NB + 255) / 256), b256, 0, stream>>>(bcounts, NB);
    k_bcount<<<dim3(NBLK), b256, 0, stream>>>(dst, bcounts, bh);
    k_bscan<<<dim3(1), b256, 0, stream>>>(bcounts, bbase, rowptr);
    k_boffset<<<dim3((NB + 3) / 4), b256, 0, stream>>>(bbase, bh);
    k_bucket<<<dim3(NBLK), b256, 0, stream>>>(src, dst, bh, bpairs);
    k_bsort<<<dim3(NB), b256, 0, stream>>>(bpairs, bbase, rowptr, csrsrc);

    const int mg_grid   = (NN + 63) / 64;     // 782
    const int g3_grid   = (NN + 15) / 16;     // 3125
    const int node_grid = (NN + 3) / 4;       // 12500

    // Layer 1
    k_mgemm<true><<<dim3(mg_grid), b256, 0, stream>>>(feat, wtg, al1, ar1, dflag, (bf16*)ftb, el, er);
    k_agg128<<<dim3(node_grid), b256, 0, stream>>>(ftb, el, er, rowptr, csrsrc, b1, dflag, hB);

    // Layer 2
    k_mgemm<false><<<dim3(mg_grid), b256, 0, stream>>>(hB, wtg + 16384, al2, ar2, dflag, (bf16*)ftb, el, er);
    k_agg128<<<dim3(node_grid), b256, 0, stream>>>(ftb, el, er, rowptr, csrsrc, b2, dflag, hB);

    // Layer 3
    k_gemm3<<<dim3(g3_grid), b256, 0, stream>>>(hB, W3, al3, ar3, dflag, (float*)ftb, el, er);
    k_agg16<<<dim3(node_grid), b256, 0, stream>>>((const float*)ftb, el, er, rowptr, csrsrc, b3, dflag, d_out);
}

// Round 14
// 340.352 us; speedup vs baseline: 1.4670x; 1.0778x over previous
//
#include <hip/hip_runtime.h>
#include <hip/hip_bf16.h>

#define NN 50000
#define NE 1600000
#define FF 128
#define CC 16
#define NB ((NN + 63) / 64)       // 782 dst-buckets of 64 nodes
#define NBLK 256                  // partition blocks for the sort (all CUs)
#define CH ((NE + NBLK - 1) / NBLK)   // 6250 edges per partition block

using bf16 = __hip_bfloat16;
using bf16x8 = __attribute__((ext_vector_type(8))) short;   // 8 bf16 = 4 VGPRs
using f32x4  = __attribute__((ext_vector_type(4))) float;

// Runtime-dtype load: isbf selects bf16 vs f32 interpretation of p.
static __device__ __forceinline__ float ldf(const void* p, int i, int isbf){
    return isbf ? __bfloat162float(((const bf16*)p)[i]) : ((const float*)p)[i];
}
static __device__ __forceinline__ float bflo(unsigned u){
    union{unsigned x; float f;} c; c.x = u << 16; return c.f;
}
static __device__ __forceinline__ float bfhi(unsigned u){
    union{unsigned x; float f;} c; c.x = u & 0xFFFF0000u; return c.f;
}
static __device__ __forceinline__ float rdlanef(float v, int l){
    return __int_as_float(__builtin_amdgcn_readlane(__float_as_int(v), l));
}
static __device__ __forceinline__ unsigned short f2bfu(float v){
    bf16 b = __float2bfloat16(v);
    union{bf16 b; unsigned short u;} c; c.b = b; return c.u;
}

// ---------------- dtype detector ----------------
__global__ __launch_bounds__(256) void k_detect(const unsigned short* __restrict__ u,
                                                int* __restrict__ flag){
    int t = threadIdx.x;
    unsigned short lo = u[2 * t];
    int e = (lo >> 7) & 0xFF;
    int sane = (e >= 117 && e <= 137) ? 1 : 0;
    __shared__ int cnt;
    if (t == 0) cnt = 0;
    __syncthreads();
    atomicAdd(&cnt, sane);
    __syncthreads();
    if (t == 0) *flag = (cnt >= 128) ? 1 : 0;   // 1 => bf16 data
}

__global__ __launch_bounds__(256) void k_zero(int* __restrict__ p, int n){
    int i = blockIdx.x * 256 + threadIdx.x;
    if (i < n) p[i] = 0;
}

// ---------------- W prep: Wt[feat][k] bf16 for W1, W2 (128x128) and W3 (16x128) ----------------
// wtg layout: [0,16384): W1t; [16384,32768): W2t; [32768,34816): W3t.
__global__ __launch_bounds__(256) void k_wprep(const void* __restrict__ W1, const void* __restrict__ W2,
                                               const void* __restrict__ W3, const int* __restrict__ dflag,
                                               unsigned short* __restrict__ wtg){
    const int isbf = *dflag;
    int idx = blockIdx.x * 256 + threadIdx.x;   // 0 .. 34815
    if (idx < 32768){
        int l = idx >> 14;                      // 0: W1, 1: W2
        int e = idx & 16383;
        int f = e >> 7, k = e & 127;
        const void* W = l ? W2 : W1;
        wtg[idx] = f2bfu(ldf(W, k * FF + f, isbf));
    } else {
        int e = idx - 32768;                    // 0 .. 2047
        int f = e >> 7, k = e & 127;
        wtg[idx] = f2bfu(ldf(W3, k * CC + f, isbf));
    }
}

// ---------------- CSR build: hierarchical counting sort by dst ----------------

__global__ __launch_bounds__(256) void k_bcount(const int* __restrict__ dst, int* __restrict__ bcounts,
                                                int* __restrict__ bh){
    __shared__ int hist[NB];
    const int t = threadIdx.x, b = blockIdx.x;
    for (int i = t; i < NB; i += 256) hist[i] = 0;
    __syncthreads();
    const int beg = b * CH, end = (beg + CH < NE) ? beg + CH : NE;
    for (int i = beg + t; i < end; i += 256){
        int d = dst[i];
        if ((unsigned)d >= NN) d = 0;
        atomicAdd(&hist[d >> 6], 1);
    }
    __syncthreads();
    for (int k = t; k < NB; k += 256){
        int v = hist[k];
        bh[k * NBLK + b] = v;
        if (v) atomicAdd(&bcounts[k], v);
    }
}

__global__ __launch_bounds__(256) void k_bscan(const int* __restrict__ bcounts, int* __restrict__ bbase,
                                               int* __restrict__ rowptr){
    __shared__ int s[256];
    const int t = threadIdx.x;
    constexpr int PT = (NB + 255) / 256;   // 4
    int loc[PT];
    int sum = 0;
    #pragma unroll
    for (int i = 0; i < PT; i++){
        int idx = t * PT + i;
        int v = (idx < NB) ? bcounts[idx] : 0;
        loc[i] = sum;
        sum += v;
    }
    s[t] = sum; __syncthreads();
    for (int off = 1; off < 256; off <<= 1){
        int x = (t >= off) ? s[t - off] : 0;
        __syncthreads();
        s[t] += x;
        __syncthreads();
    }
    int base = (t > 0) ? s[t - 1] : 0;
    #pragma unroll
    for (int i = 0; i < PT; i++){
        int idx = t * PT + i;
        if (idx < NB) bbase[idx] = base + loc[i];
    }
    if (t == 255){
        bbase[NB] = s[255];      // == NE
        rowptr[NN] = s[255];
    }
}

// Per-bucket offsets: wave-per-bucket shfl scan over the 256 per-block counts (4/lane).
__global__ __launch_bounds__(256) void k_boffset(const int* __restrict__ bbase, int* __restrict__ bh){
    int k = blockIdx.x * 4 + (threadIdx.x >> 6);
    int lane = threadIdx.x & 63;
    if (k >= NB) return;
    int v[4];
    int s = 0;
    #pragma unroll
    for (int i = 0; i < 4; i++){
        v[i] = bh[k * NBLK + 4 * lane + i];
        s += v[i];
    }
    int tot = s;
    #pragma unroll
    for (int off = 1; off < 64; off <<= 1){
        int x = __shfl_up(s, off);
        if (lane >= off) s += x;
    }
    int run = bbase[k] + s - tot;   // exclusive prefix of per-lane sums
    #pragma unroll
    for (int i = 0; i < 4; i++){
        bh[k * NBLK + 4 * lane + i] = run;
        run += v[i];
    }
}

__global__ __launch_bounds__(256) void k_bucket(const int* __restrict__ src, const int* __restrict__ dst,
                                                const int* __restrict__ bh, unsigned* __restrict__ bpairs){
    __shared__ int cur[NB];
    const int t = threadIdx.x, b = blockIdx.x;
    for (int k = t; k < NB; k += 256) cur[k] = bh[k * NBLK + b];
    __syncthreads();
    const int beg = b * CH, end = (beg + CH < NE) ? beg + CH : NE;
    for (int i = beg + t; i < end; i += 256){
        int s = src[i];
        int d = dst[i];
        if ((unsigned)s >= NN) s = 0;
        if ((unsigned)d >= NN) d = 0;
        int p = atomicAdd(&cur[d >> 6], 1);
        if ((unsigned)p < NE) bpairs[p] = (unsigned)s | ((unsigned)(d & 63) << 16);
    }
}

__global__ __launch_bounds__(256) void k_bsort(const unsigned* __restrict__ bpairs, const int* __restrict__ bbase,
                                               int* __restrict__ rowptr, int* __restrict__ csrsrc){
    __shared__ int cnt[64];
    __shared__ int cur[64];
    const int t = threadIdx.x;
    const int b = blockIdx.x;
    const int base = bbase[b];
    const int endb = bbase[b + 1];
    if (t < 64) cnt[t] = 0;
    __syncthreads();
    for (int i = base + t; i < endb; i += 256)
        atomicAdd(&cnt[bpairs[i] >> 16], 1);
    __syncthreads();
    if (t < 64){   // wave 0 exactly: 64-lane exclusive scan via shfl
        int v = cnt[t];
        int inc = v;
        #pragma unroll
        for (int off = 1; off < 64; off <<= 1){
            int x = __shfl_up(inc, off);
            if (t >= off) inc += x;
        }
        int excl = inc - v;
        cur[t] = excl;
        int d = b * 64 + t;
        if (d < NN) rowptr[d] = base + excl;
    }
    __syncthreads();
    for (int i = base + t; i < endb; i += 256){
        unsigned pr = bpairs[i];
        int p = atomicAdd(&cur[pr >> 16], 1);
        csrsrc[base + p] = (int)(pr & 0xFFFFu);
    }
}

// ---------------- MFMA GEMM (layers 1-2): ft = X @ W, bf16 in / f32 acc / bf16 out ----------------

#define XPAD 136   // 17*8: keeps 16B alignment, breaks bank stride

template<bool XDYN>
__global__ __launch_bounds__(256) void k_mgemm(const void* __restrict__ X, const unsigned short* __restrict__ wtg,
                                               const void* __restrict__ al, const void* __restrict__ ar,
                                               const int* __restrict__ dflag, bf16* __restrict__ ft,
                                               float* __restrict__ el, float* __restrict__ er){
    __shared__ unsigned short xs[64 * XPAD];
    __shared__ unsigned short wt[128 * XPAD];
    const int isbf = *dflag;
    const int t  = threadIdx.x;
    const int n0 = blockIdx.x * 64;

    for (int i2 = t; i2 < 8192; i2 += 256){
        unsigned v = ((const unsigned*)wtg)[i2];
        int r = i2 >> 6, c2 = (i2 & 63) * 2;
        *(unsigned*)&wt[r * XPAD + c2] = v;
    }
    for (int i2 = t; i2 < 4096; i2 += 256){
        int r = i2 >> 6, c2 = (i2 & 63) * 2;
        int n = n0 + r;
        float v0 = 0.f, v1 = 0.f;
        if (n < NN){
            if (XDYN){ v0 = ldf(X, n * FF + c2, isbf); v1 = ldf(X, n * FF + c2 + 1, isbf); }
            else     { v0 = ((const float*)X)[n * FF + c2]; v1 = ((const float*)X)[n * FF + c2 + 1]; }
        }
        unsigned pk = (unsigned)f2bfu(v0) | ((unsigned)f2bfu(v1) << 16);
        *(unsigned*)&xs[r * XPAD + c2] = pk;
    }
    __syncthreads();

    const int wv = t >> 6;
    const int lane = t & 63;
    const int quad = lane >> 4;
    const int mcol = lane & 15;

    bf16x8 afr[4];
    const unsigned short* xrow = &xs[(wv * 16 + mcol) * XPAD + quad * 8];
    #pragma unroll
    for (int kt = 0; kt < 4; kt++)
        afr[kt] = *(const bf16x8*)(xrow + kt * 32);

    float elp[4] = {0.f,0.f,0.f,0.f}, erp[4] = {0.f,0.f,0.f,0.f};

    #pragma unroll
    for (int f = 0; f < 8; f++){
        f32x4 acc = {0.f, 0.f, 0.f, 0.f};
        const unsigned short* wrow = &wt[(f * 16 + mcol) * XPAD + quad * 8];
        #pragma unroll
        for (int kt = 0; kt < 4; kt++){
            bf16x8 bfr = *(const bf16x8*)(wrow + kt * 32);
            acc = __builtin_amdgcn_mfma_f32_16x16x32_bf16(afr[kt], bfr, acc, 0, 0, 0);
        }
        int col = f * 16 + mcol;
        float alv = ldf(al, col, isbf);
        float arv = ldf(ar, col, isbf);
        #pragma unroll
        for (int reg = 0; reg < 4; reg++){
            int node = n0 + wv * 16 + quad * 4 + reg;
            float v = acc[reg];
            if (node < NN) ft[node * FF + col] = __float2bfloat16(v);
            elp[reg] += v * alv;
            erp[reg] += v * arv;
        }
    }

    #pragma unroll
    for (int reg = 0; reg < 4; reg++){
        float pl = elp[reg], pr = erp[reg];
        #pragma unroll
        for (int off = 1; off < 16; off <<= 1){
            pl += __shfl_xor(pl, off);
            pr += __shfl_xor(pr, off);
        }
        int node = n0 + wv * 16 + quad * 4 + reg;
        if (mcol == 0 && node < NN){ el[node] = pl; er[node] = pr; }
    }
}

// ---------------- MFMA GEMM (layer 3): ft3 = X @ W3, bf16 in / f32 acc / f32 out ----------------
// Same fragment/epilogue layout as k_mgemm, single 16-col output tile.

__global__ __launch_bounds__(256) void k_mgemm3(const float* __restrict__ X, const unsigned short* __restrict__ wt3g,
                                                const void* __restrict__ al, const void* __restrict__ ar,
                                                const int* __restrict__ dflag, float* __restrict__ ft,
                                                float* __restrict__ el, float* __restrict__ er){
    __shared__ unsigned short xs[64 * XPAD];
    __shared__ unsigned short wt[16 * XPAD];
    const int isbf = *dflag;
    const int t  = threadIdx.x;
    const int n0 = blockIdx.x * 64;

    for (int i2 = t; i2 < 1024; i2 += 256){
        unsigned v = ((const unsigned*)wt3g)[i2];
        int r = i2 >> 6, c2 = (i2 & 63) * 2;
        *(unsigned*)&wt[r * XPAD + c2] = v;
    }
    for (int i2 = t; i2 < 4096; i2 += 256){
        int r = i2 >> 6, c2 = (i2 & 63) * 2;
        int n = n0 + r;
        float v0 = 0.f, v1 = 0.f;
        if (n < NN){
            v0 = X[n * FF + c2];
            v1 = X[n * FF + c2 + 1];
        }
        unsigned pk = (unsigned)f2bfu(v0) | ((unsigned)f2bfu(v1) << 16);
        *(unsigned*)&xs[r * XPAD + c2] = pk;
    }
    __syncthreads();

    const int wv = t >> 6;
    const int lane = t & 63;
    const int quad = lane >> 4;
    const int mcol = lane & 15;

    f32x4 acc = {0.f, 0.f, 0.f, 0.f};
    const unsigned short* xrow = &xs[(wv * 16 + mcol) * XPAD + quad * 8];
    const unsigned short* wrow = &wt[mcol * XPAD + quad * 8];
    #pragma unroll
    for (int kt = 0; kt < 4; kt++){
        bf16x8 afr = *(const bf16x8*)(xrow + kt * 32);
        bf16x8 bfr = *(const bf16x8*)(wrow + kt * 32);
        acc = __builtin_amdgcn_mfma_f32_16x16x32_bf16(afr, bfr, acc, 0, 0, 0);
    }

    float alv = ldf(al, mcol, isbf);
    float arv = ldf(ar, mcol, isbf);
    #pragma unroll
    for (int reg = 0; reg < 4; reg++){
        int node = n0 + wv * 16 + quad * 4 + reg;
        float v = acc[reg];
        if (node < NN) ft[node * CC + mcol] = v;
        float pl = v * alv, pr = v * arv;
        #pragma unroll
        for (int off = 1; off < 16; off <<= 1){
            pl += __shfl_xor(pl, off);
            pr += __shfl_xor(pr, off);
        }
        if (mcol == 0 && node < NN){ el[node] = pl; er[node] = pr; }
    }
}

// ---------------- Aggregation (128 feats, bf16 ft): round-9 proven kernel ----------------

__global__ __launch_bounds__(256) void k_agg128(const void* __restrict__ ftv, const float* __restrict__ el,
                                                const float* __restrict__ er, const int* __restrict__ rowptr,
                                                const int* __restrict__ csrsrc, const void* __restrict__ bias,
                                                const int* __restrict__ dflag, float* __restrict__ outp){
    const int isbf = *dflag;
    int lane = threadIdx.x & 63;
    int n = blockIdx.x * 4 + (threadIdx.x >> 6);
    if (n >= NN) return;
    int beg = rowptr[n], end = rowptr[n + 1];
    beg = (beg < 0) ? 0 : (beg > NE ? NE : beg);
    end = (end < beg) ? beg : (end > NE ? NE : end);
    int deg = end - beg;
    float erd = er[n];

    float m = -3.4e38f;
    int   s_c = 0;
    float e_c = 0.f;
    for (int i = beg + lane; i < end; i += 64){
        int s = csrsrc[i];
        if ((unsigned)s >= NN) s = 0;
        float e = el[s] + erd;
        e = (e >= 0.f) ? e : 0.2f * e;
        if (i < beg + 64){ s_c = s; e_c = e; }
        m = fmaxf(m, e);
    }
    #pragma unroll
    for (int off = 32; off; off >>= 1) m = fmaxf(m, __shfl_xor(m, off));

    int jmax = (deg < 64) ? deg : 64;
    float w_c = (lane < jmax) ? __expf(e_c - m) : 0.f;
    float lsum = w_c;
    #pragma unroll
    for (int off = 32; off; off >>= 1) lsum += __shfl_xor(lsum, off);

    const unsigned* ftb = (const unsigned*)ftv;
    float acc0 = 0.f, acc1 = 0.f;
    int j = 0;
    if (jmax >= 8){
        float w[8]; unsigned u[8];
        #pragma unroll
        for (int q = 0; q < 8; q++){
            int s = __builtin_amdgcn_readlane(s_c, q);
            w[q] = rdlanef(w_c, q);
            u[q] = (ftb + s * 64)[lane];
        }
        for (j = 8; j + 8 <= jmax; j += 8){
            float wn[8]; unsigned un[8];
            #pragma unroll
            for (int q = 0; q < 8; q++){
                int s = __builtin_amdgcn_readlane(s_c, j + q);
                wn[q] = rdlanef(w_c, j + q);
                un[q] = (ftb + s * 64)[lane];
            }
            #pragma unroll
            for (int q = 0; q < 8; q++){
                acc0 += w[q] * bflo(u[q]);
                acc1 += w[q] * bfhi(u[q]);
                w[q] = wn[q]; u[q] = un[q];
            }
        }
        #pragma unroll
        for (int q = 0; q < 8; q++){
            acc0 += w[q] * bflo(u[q]);
            acc1 += w[q] * bfhi(u[q]);
        }
    }
    for (; j < jmax; ++j){
        int s = __builtin_amdgcn_readlane(s_c, j);
        float w = rdlanef(w_c, j);
        unsigned u = (ftb + s * 64)[lane];
        acc0 += w * bflo(u); acc1 += w * bfhi(u);
    }
    for (int i = beg + 64; i < end; ++i){
        int s = csrsrc[i];
        if ((unsigned)s >= NN) s = 0;
        float e = el[s] + erd;
        e = (e >= 0.f) ? e : 0.2f * e;
        float w = __expf(e - m);
        unsigned u = (ftb + s * 64)[lane];
        lsum += w;
        acc0 += w * bflo(u); acc1 += w * bfhi(u);
    }
    float inv = 1.f / ((lsum > 0.f) ? lsum : 1.f);
    float2 o;
    o.x = fmaxf(acc0 * inv + ldf(bias, 2 * lane,     isbf), 0.f);
    o.y = fmaxf(acc1 * inv + ldf(bias, 2 * lane + 1, isbf), 0.f);
    ((float2*)outp)[n * 64 + lane] = o;
}

// ---------------- Aggregation (16 feats, f32 ft): 4-lane edge groups, final output ----------------

__global__ __launch_bounds__(256) void k_agg16(const float* __restrict__ ftv, const float* __restrict__ el,
                                               const float* __restrict__ er, const int* __restrict__ rowptr,
                                               const int* __restrict__ csrsrc, const void* __restrict__ bias,
                                               const int* __restrict__ dflag, void* __restrict__ outp){
    const int isbf = *dflag;
    int lane = threadIdx.x & 63;
    int n = blockIdx.x * 4 + (threadIdx.x >> 6);
    if (n >= NN) return;
    int beg = rowptr[n], end = rowptr[n + 1];
    beg = (beg < 0) ? 0 : (beg > NE ? NE : beg);
    end = (end < beg) ? beg : (end > NE ? NE : end);
    int deg = end - beg;
    float erd = er[n];

    float m = -3.4e38f;
    int   s_c = 0;
    float e_c = 0.f;
    for (int i = beg + lane; i < end; i += 64){
        int s = csrsrc[i];
        if ((unsigned)s >= NN) s = 0;
        float e = el[s] + erd;
        e = (e >= 0.f) ? e : 0.2f * e;
        if (i < beg + 64){ s_c = s; e_c = e; }
        m = fmaxf(m, e);
    }
    #pragma unroll
    for (int off = 32; off; off >>= 1) m = fmaxf(m, __shfl_xor(m, off));

    int jmax = (deg < 64) ? deg : 64;
    float w_c = (lane < jmax) ? __expf(e_c - m) : 0.f;
    float lsum = w_c;
    #pragma unroll
    for (int off = 32; off; off >>= 1) lsum += __shfl_xor(lsum, off);

    const float4* ftq = (const float4*)ftv;   // row n at ftq[n*4 + fl2]
    const int g   = lane >> 2;    // edge-in-batch 0..15
    const int fl2 = lane & 3;
    int nbatch = (jmax + 15) >> 4;    // <= 4
    float wq[4]; float4 uq[4];
    #pragma unroll
    for (int q = 0; q < 4; q++){
        int eidx = (q * 16 + g) & 63;
        int s = __shfl(s_c, eidx);
        wq[q] = (q < nbatch) ? __shfl(w_c, eidx) : 0.f;
        uq[q] = ftq[(unsigned)s * 4 + fl2];
    }
    float a4[4] = {0.f,0.f,0.f,0.f};
    #pragma unroll
    for (int q = 0; q < 4; q++){
        a4[0] += wq[q] * uq[q].x;
        a4[1] += wq[q] * uq[q].y;
        a4[2] += wq[q] * uq[q].z;
        a4[3] += wq[q] * uq[q].w;
    }
    for (int i = beg + 64; i < end; ++i){
        int s = csrsrc[i];
        if ((unsigned)s >= NN) s = 0;
        float e = el[s] + erd;
        e = (e >= 0.f) ? e : 0.2f * e;
        float w = __expf(e - m);
        lsum += w;
        if (g == 0){
            float4 u = ftq[(unsigned)s * 4 + fl2];
            a4[0] += w * u.x; a4[1] += w * u.y; a4[2] += w * u.z; a4[3] += w * u.w;
        }
    }
    #pragma unroll
    for (int i = 0; i < 4; i++){
        a4[i] += __shfl_xor(a4[i], 4);
        a4[i] += __shfl_xor(a4[i], 8);
        a4[i] += __shfl_xor(a4[i], 16);
        a4[i] += __shfl_xor(a4[i], 32);
    }
    float inv = 1.f / ((lsum > 0.f) ? lsum : 1.f);
    if (lane < 4){
        float o0 = fmaxf(a4[0] * inv + ldf(bias, fl2 * 4 + 0, isbf), 0.f);
        float o1 = fmaxf(a4[1] * inv + ldf(bias, fl2 * 4 + 1, isbf), 0.f);
        float o2 = fmaxf(a4[2] * inv + ldf(bias, fl2 * 4 + 2, isbf), 0.f);
        float o3 = fmaxf(a4[3] * inv + ldf(bias, fl2 * 4 + 3, isbf), 0.f);
        if (isbf){
            uint2 pk;
            pk.x = (unsigned)f2bfu(o0) | ((unsigned)f2bfu(o1) << 16);
            pk.y = (unsigned)f2bfu(o2) | ((unsigned)f2bfu(o3) << 16);
            ((uint2*)outp)[n * 4 + fl2] = pk;
        } else {
            float4 o; o.x = o0; o.y = o1; o.z = o2; o.w = o3;
            ((float4*)outp)[n * 4 + fl2] = o;
        }
    }
}

// ---------------- host launch ----------------

static size_t align256(size_t x){ return (x + 255) & ~(size_t)255; }

extern "C" void kernel_launch(void* const* d_in, const int* in_sizes, int n_in,
                              void* d_out, int out_size, void* d_ws, size_t ws_size,
                              hipStream_t stream) {
    const void* feat = d_in[0];
    const int*  src  = (const int*)d_in[1];
    const int*  dst  = (const int*)d_in[2];
    const void* W1 = d_in[3];
    const void* al1= d_in[4];
    const void* ar1= d_in[5];
    const void* b1 = d_in[6];
    const void* W2 = d_in[7];
    const void* al2= d_in[8];
    const void* ar2= d_in[9];
    const void* b2 = d_in[10];
    const void* W3 = d_in[11];
    const void* al3= d_in[12];
    const void* ar3= d_in[13];
    const void* b3 = d_in[14];

    // workspace carve
    char* p = (char*)d_ws;
    size_t off = 0;
    auto carve = [&](size_t bytes)->void*{
        void* r = p + off;
        off += align256(bytes);
        return r;
    };
    float* ftA   = (float*)carve((size_t)NN * FF * 4);   // ft buffer: bf16 view (layers 1/2), f32 view (layer 3)
    float* hB    = (float*)carve((size_t)NN * FF * 4);   // hidden state; bpairs overlays it pre-layer-1
    float* el    = (float*)carve((size_t)NN * 4);
    float* er    = (float*)carve((size_t)NN * 4);
    int*   rowptr= (int*)  carve((size_t)(NN + 1) * 4);
    int*   csrsrc= (int*)  carve((size_t)NE * 4);
    int*   bcounts=(int*)  carve((size_t)NB * 4);
    int*   bbase  =(int*)  carve((size_t)(NB + 1) * 4);
    int*   bh     =(int*)  carve((size_t)NB * NBLK * 4);  // per-(bucket,block) hist/offsets, 800KB
    unsigned short* wtg = (unsigned short*)carve((size_t)34816 * 2);  // W1t,W2t,W3t bf16
    int*   dflag  =(int*)  carve(256);
    unsigned* bpairs = (unsigned*)hB;   // overlay: consumed before hB is first written
    void*  ftb   = ftA;                 // bf16 ft view (layers 1-2); f32 ft3 view (layer 3)
    (void)ws_size; (void)n_in; (void)in_sizes; (void)out_size;

    dim3 b256(256);

    k_detect<<<dim3(1), b256, 0, stream>>>((const unsigned short*)feat, dflag);
    k_wprep<<<dim3(136), b256, 0, stream>>>(W1, W2, W3, dflag, wtg);

    // CSR build via hierarchical counting sort
    k_zero<<<dim3((NB + 255) / 256), b256, 0, stream>>>(bcounts, NB);
    k_bcount<<<dim3(NBLK), b256, 0, stream>>>(dst, bcounts, bh);
    k_bscan<<<dim3(1), b256, 0, stream>>>(bcounts, bbase, rowptr);
    k_boffset<<<dim3((NB + 3) / 4), b256, 0, stream>>>(bbase, bh);
    k_bucket<<<dim3(NBLK), b256, 0, stream>>>(src, dst, bh, bpairs);
    k_bsort<<<dim3(NB), b256, 0, stream>>>(bpairs, bbase, rowptr, csrsrc);

    const int mg_grid   = (NN + 63) / 64;     // 782
    const int node_grid = (NN + 3) / 4;       // 12500

    // Layer 1
    k_mgemm<true><<<dim3(mg_grid), b256, 0, stream>>>(feat, wtg, al1, ar1, dflag, (bf16*)ftb, el, er);
    k_agg128<<<dim3(node_grid), b256, 0, stream>>>(ftb, el, er, rowptr, csrsrc, b1, dflag, hB);

    // Layer 2
    k_mgemm<false><<<dim3(mg_grid), b256, 0, stream>>>(hB, wtg + 16384, al2, ar2, dflag, (bf16*)ftb, el, er);
    k_agg128<<<dim3(node_grid), b256, 0, stream>>>(ftb, el, er, rowptr, csrsrc, b2, dflag, hB);

    // Layer 3 (MFMA, f32 out)
    k_mgemm3<<<dim3(mg_grid), b256, 0, stream>>>(hB, wtg + 32768, al3, ar3, dflag, (float*)ftb, el, er);
    k_agg16<<<dim3(node_grid), b256, 0, stream>>>((const float*)ftb, el, er, rowptr, csrsrc, b3, dflag, d_out);
}

// Round 15
// 339.869 us; speedup vs baseline: 1.4691x; 1.0014x over previous
//
#include <hip/hip_runtime.h>
#include <hip/hip_bf16.h>

#define NN 50000
#define NE 1600000
#define FF 128
#define CC 16
#define NB ((NN + 63) / 64)       // 782 dst-buckets of 64 nodes
#define NBLK 256                  // partition blocks for the sort (all CUs)
#define CH ((NE + NBLK - 1) / NBLK)   // 6250 edges per partition block

using bf16 = __hip_bfloat16;
using bf16x8 = __attribute__((ext_vector_type(8))) short;   // 8 bf16 = 4 VGPRs
using f32x4  = __attribute__((ext_vector_type(4))) float;

// Runtime-dtype load: isbf selects bf16 vs f32 interpretation of p.
static __device__ __forceinline__ float ldf(const void* p, int i, int isbf){
    return isbf ? __bfloat162float(((const bf16*)p)[i]) : ((const float*)p)[i];
}
static __device__ __forceinline__ float bflo(unsigned u){
    union{unsigned x; float f;} c; c.x = u << 16; return c.f;
}
static __device__ __forceinline__ float bfhi(unsigned u){
    union{unsigned x; float f;} c; c.x = u & 0xFFFF0000u; return c.f;
}
static __device__ __forceinline__ float rdlanef(float v, int l){
    return __int_as_float(__builtin_amdgcn_readlane(__float_as_int(v), l));
}
static __device__ __forceinline__ unsigned short f2bfu(float v){
    bf16 b = __float2bfloat16(v);
    union{bf16 b; unsigned short u;} c; c.b = b; return c.u;
}

// ---------------- fused prep: dtype detect + bcounts zero + W1/W2/W3 transpose->bf16 ----------------
// Each block re-derives the dtype flag locally (no cross-kernel dependency);
// block 0 publishes dflag for downstream kernels; blocks 0-3 zero bcounts.
__global__ __launch_bounds__(256) void k_prep(const unsigned short* __restrict__ featu,
                                              const void* __restrict__ W1, const void* __restrict__ W2,
                                              const void* __restrict__ W3, int* __restrict__ dflag,
                                              int* __restrict__ bcounts, unsigned short* __restrict__ wtg){
    __shared__ int cnt;
    const int t = threadIdx.x;
    if (t == 0) cnt = 0;
    __syncthreads();
    unsigned short lo = featu[2 * t];
    int e = (lo >> 7) & 0xFF;
    if (e >= 117 && e <= 137) atomicAdd(&cnt, 1);
    __syncthreads();
    const int isbf = (cnt >= 128) ? 1 : 0;   // 1 => bf16 inputs
    int idx = blockIdx.x * 256 + t;
    if (idx == 0) *dflag = isbf;
    if (idx < NB) bcounts[idx] = 0;
    if (idx < 32768){
        int l = idx >> 14;                   // 0: W1, 1: W2
        int e2 = idx & 16383;
        int f = e2 >> 7, k = e2 & 127;
        const void* W = l ? W2 : W1;
        wtg[idx] = f2bfu(ldf(W, k * FF + f, isbf));
    } else if (idx < 34816){
        int e2 = idx - 32768;                // W3t: 16x128
        int f = e2 >> 7, k = e2 & 127;
        wtg[idx] = f2bfu(ldf(W3, k * CC + f, isbf));
    }
}

// ---------------- CSR build: hierarchical counting sort by dst ----------------

__global__ __launch_bounds__(256) void k_bcount(const int* __restrict__ dst, int* __restrict__ bcounts,
                                                int* __restrict__ bh){
    __shared__ int hist[NB];
    const int t = threadIdx.x, b = blockIdx.x;
    for (int i = t; i < NB; i += 256) hist[i] = 0;
    __syncthreads();
    const int beg = b * CH, end = (beg + CH < NE) ? beg + CH : NE;
    for (int i = beg + t; i < end; i += 256){
        int d = dst[i];
        if ((unsigned)d >= NN) d = 0;
        atomicAdd(&hist[d >> 6], 1);
    }
    __syncthreads();
    for (int k = t; k < NB; k += 256){
        int v = hist[k];
        bh[k * NBLK + b] = v;
        if (v) atomicAdd(&bcounts[k], v);
    }
}

__global__ __launch_bounds__(256) void k_bscan(const int* __restrict__ bcounts, int* __restrict__ bbase,
                                               int* __restrict__ rowptr){
    __shared__ int s[256];
    const int t = threadIdx.x;
    constexpr int PT = (NB + 255) / 256;   // 4
    int loc[PT];
    int sum = 0;
    #pragma unroll
    for (int i = 0; i < PT; i++){
        int idx = t * PT + i;
        int v = (idx < NB) ? bcounts[idx] : 0;
        loc[i] = sum;
        sum += v;
    }
    s[t] = sum; __syncthreads();
    for (int off = 1; off < 256; off <<= 1){
        int x = (t >= off) ? s[t - off] : 0;
        __syncthreads();
        s[t] += x;
        __syncthreads();
    }
    int base = (t > 0) ? s[t - 1] : 0;
    #pragma unroll
    for (int i = 0; i < PT; i++){
        int idx = t * PT + i;
        if (idx < NB) bbase[idx] = base + loc[i];
    }
    if (t == 255){
        bbase[NB] = s[255];      // == NE
        rowptr[NN] = s[255];
    }
}

// Per-bucket offsets: wave-per-bucket shfl scan over the 256 per-block counts (4/lane).
__global__ __launch_bounds__(256) void k_boffset(const int* __restrict__ bbase, int* __restrict__ bh){
    int k = blockIdx.x * 4 + (threadIdx.x >> 6);
    int lane = threadIdx.x & 63;
    if (k >= NB) return;
    int v[4];
    int s = 0;
    #pragma unroll
    for (int i = 0; i < 4; i++){
        v[i] = bh[k * NBLK + 4 * lane + i];
        s += v[i];
    }
    int tot = s;
    #pragma unroll
    for (int off = 1; off < 64; off <<= 1){
        int x = __shfl_up(s, off);
        if (lane >= off) s += x;
    }
    int run = bbase[k] + s - tot;   // exclusive prefix of per-lane sums
    #pragma unroll
    for (int i = 0; i < 4; i++){
        bh[k * NBLK + 4 * lane + i] = run;
        run += v[i];
    }
}

__global__ __launch_bounds__(256) void k_bucket(const int* __restrict__ src, const int* __restrict__ dst,
                                                const int* __restrict__ bh, unsigned* __restrict__ bpairs){
    __shared__ int cur[NB];
    const int t = threadIdx.x, b = blockIdx.x;
    for (int k = t; k < NB; k += 256) cur[k] = bh[k * NBLK + b];
    __syncthreads();
    const int beg = b * CH, end = (beg + CH < NE) ? beg + CH : NE;
    for (int i = beg + t; i < end; i += 256){
        int s = src[i];
        int d = dst[i];
        if ((unsigned)s >= NN) s = 0;
        if ((unsigned)d >= NN) d = 0;
        int p = atomicAdd(&cur[d >> 6], 1);
        if ((unsigned)p < NE) bpairs[p] = (unsigned)s | ((unsigned)(d & 63) << 16);
    }
}

__global__ __launch_bounds__(256) void k_bsort(const unsigned* __restrict__ bpairs, const int* __restrict__ bbase,
                                               int* __restrict__ rowptr, int* __restrict__ csrsrc){
    __shared__ int cnt[64];
    __shared__ int cur[64];
    const int t = threadIdx.x;
    const int b = blockIdx.x;
    const int base = bbase[b];
    const int endb = bbase[b + 1];
    if (t < 64) cnt[t] = 0;
    __syncthreads();
    for (int i = base + t; i < endb; i += 256)
        atomicAdd(&cnt[bpairs[i] >> 16], 1);
    __syncthreads();
    if (t < 64){   // wave 0 exactly: 64-lane exclusive scan via shfl
        int v = cnt[t];
        int inc = v;
        #pragma unroll
        for (int off = 1; off < 64; off <<= 1){
            int x = __shfl_up(inc, off);
            if (t >= off) inc += x;
        }
        int excl = inc - v;
        cur[t] = excl;
        int d = b * 64 + t;
        if (d < NN) rowptr[d] = base + excl;
    }
    __syncthreads();
    for (int i = base + t; i < endb; i += 256){
        unsigned pr = bpairs[i];
        int p = atomicAdd(&cur[pr >> 16], 1);
        csrsrc[base + p] = (int)(pr & 0xFFFFu);
    }
}

// ---------------- MFMA GEMM (layers 1-2): ft = X @ W, bf16 in / f32 acc / bf16 out ----------------
// XDYN=true: X is runtime-dtype (layer 1); XDYN=false: X is bf16-packed workspace
// (layer 2) — staging is a pure uint copy, no conversions.

#define XPAD 136   // 17*8: keeps 16B alignment, breaks bank stride

template<bool XDYN>
__global__ __launch_bounds__(256) void k_mgemm(const void* __restrict__ X, const unsigned short* __restrict__ wtg,
                                               const void* __restrict__ al, const void* __restrict__ ar,
                                               const int* __restrict__ dflag, bf16* __restrict__ ft,
                                               float* __restrict__ el, float* __restrict__ er){
    __shared__ unsigned short xs[64 * XPAD];
    __shared__ unsigned short wt[128 * XPAD];
    const int isbf = *dflag;
    const int t  = threadIdx.x;
    const int n0 = blockIdx.x * 64;

    for (int i2 = t; i2 < 8192; i2 += 256){
        unsigned v = ((const unsigned*)wtg)[i2];
        int r = i2 >> 6, c2 = (i2 & 63) * 2;
        *(unsigned*)&wt[r * XPAD + c2] = v;
    }
    for (int i2 = t; i2 < 4096; i2 += 256){
        int r = i2 >> 6, c2 = (i2 & 63) * 2;
        int n = n0 + r;
        unsigned pk = 0u;
        if (n < NN){
            if (XDYN){
                float v0 = ldf(X, n * FF + c2, isbf);
                float v1 = ldf(X, n * FF + c2 + 1, isbf);
                pk = (unsigned)f2bfu(v0) | ((unsigned)f2bfu(v1) << 16);
            } else {
                pk = ((const unsigned*)X)[n * 64 + (i2 & 63)];   // bf16-packed copy
            }
        }
        *(unsigned*)&xs[r * XPAD + c2] = pk;
    }
    __syncthreads();

    const int wv = t >> 6;
    const int lane = t & 63;
    const int quad = lane >> 4;
    const int mcol = lane & 15;

    bf16x8 afr[4];
    const unsigned short* xrow = &xs[(wv * 16 + mcol) * XPAD + quad * 8];
    #pragma unroll
    for (int kt = 0; kt < 4; kt++)
        afr[kt] = *(const bf16x8*)(xrow + kt * 32);

    float elp[4] = {0.f,0.f,0.f,0.f}, erp[4] = {0.f,0.f,0.f,0.f};

    #pragma unroll
    for (int f = 0; f < 8; f++){
        f32x4 acc = {0.f, 0.f, 0.f, 0.f};
        const unsigned short* wrow = &wt[(f * 16 + mcol) * XPAD + quad * 8];
        #pragma unroll
        for (int kt = 0; kt < 4; kt++){
            bf16x8 bfr = *(const bf16x8*)(wrow + kt * 32);
            acc = __builtin_amdgcn_mfma_f32_16x16x32_bf16(afr[kt], bfr, acc, 0, 0, 0);
        }
        int col = f * 16 + mcol;
        float alv = ldf(al, col, isbf);
        float arv = ldf(ar, col, isbf);
        #pragma unroll
        for (int reg = 0; reg < 4; reg++){
            int node = n0 + wv * 16 + quad * 4 + reg;
            float v = acc[reg];
            if (node < NN) ft[node * FF + col] = __float2bfloat16(v);
            elp[reg] += v * alv;
            erp[reg] += v * arv;
        }
    }

    #pragma unroll
    for (int reg = 0; reg < 4; reg++){
        float pl = elp[reg], pr = erp[reg];
        #pragma unroll
        for (int off = 1; off < 16; off <<= 1){
            pl += __shfl_xor(pl, off);
            pr += __shfl_xor(pr, off);
        }
        int node = n0 + wv * 16 + quad * 4 + reg;
        if (mcol == 0 && node < NN){ el[node] = pl; er[node] = pr; }
    }
}

// ---------------- MFMA GEMM (layer 3): ft3 = X(bf16) @ W3, f32 out ----------------

__global__ __launch_bounds__(256) void k_mgemm3(const void* __restrict__ X, const unsigned short* __restrict__ wt3g,
                                                const void* __restrict__ al, const void* __restrict__ ar,
                                                const int* __restrict__ dflag, float* __restrict__ ft,
                                                float* __restrict__ el, float* __restrict__ er){
    __shared__ unsigned short xs[64 * XPAD];
    __shared__ unsigned short wt[16 * XPAD];
    const int isbf = *dflag;
    const int t  = threadIdx.x;
    const int n0 = blockIdx.x * 64;

    for (int i2 = t; i2 < 1024; i2 += 256){
        unsigned v = ((const unsigned*)wt3g)[i2];
        int r = i2 >> 6, c2 = (i2 & 63) * 2;
        *(unsigned*)&wt[r * XPAD + c2] = v;
    }
    for (int i2 = t; i2 < 4096; i2 += 256){
        int r = i2 >> 6, c2 = (i2 & 63) * 2;
        int n = n0 + r;
        unsigned pk = (n < NN) ? ((const unsigned*)X)[n * 64 + (i2 & 63)] : 0u;
        *(unsigned*)&xs[r * XPAD + c2] = pk;
    }
    __syncthreads();

    const int wv = t >> 6;
    const int lane = t & 63;
    const int quad = lane >> 4;
    const int mcol = lane & 15;

    f32x4 acc = {0.f, 0.f, 0.f, 0.f};
    const unsigned short* xrow = &xs[(wv * 16 + mcol) * XPAD + quad * 8];
    const unsigned short* wrow = &wt[mcol * XPAD + quad * 8];
    #pragma unroll
    for (int kt = 0; kt < 4; kt++){
        bf16x8 afr = *(const bf16x8*)(xrow + kt * 32);
        bf16x8 bfr = *(const bf16x8*)(wrow + kt * 32);
        acc = __builtin_amdgcn_mfma_f32_16x16x32_bf16(afr, bfr, acc, 0, 0, 0);
    }

    float alv = ldf(al, mcol, isbf);
    float arv = ldf(ar, mcol, isbf);
    #pragma unroll
    for (int reg = 0; reg < 4; reg++){
        int node = n0 + wv * 16 + quad * 4 + reg;
        float v = acc[reg];
        if (node < NN) ft[node * CC + mcol] = v;
        float pl = v * alv, pr = v * arv;
        #pragma unroll
        for (int off = 1; off < 16; off <<= 1){
            pl += __shfl_xor(pl, off);
            pr += __shfl_xor(pr, off);
        }
        if (mcol == 0 && node < NN){ el[node] = pl; er[node] = pr; }
    }
}

// ---------------- Aggregation (128 feats, bf16 ft): round-9 proven kernel, bf16 output ----------------
// h = relu(agg/lsum + bias) is written bf16-packed — numerically identical to the
// old f32 write + bf16 staging round in the consumer GEMM.

__global__ __launch_bounds__(256) void k_agg128(const void* __restrict__ ftv, const float* __restrict__ el,
                                                const float* __restrict__ er, const int* __restrict__ rowptr,
                                                const int* __restrict__ csrsrc, const void* __restrict__ bias,
                                                const int* __restrict__ dflag, unsigned* __restrict__ outp){
    const int isbf = *dflag;
    int lane = threadIdx.x & 63;
    int n = blockIdx.x * 4 + (threadIdx.x >> 6);
    if (n >= NN) return;
    int beg = rowptr[n], end = rowptr[n + 1];
    beg = (beg < 0) ? 0 : (beg > NE ? NE : beg);
    end = (end < beg) ? beg : (end > NE ? NE : end);
    int deg = end - beg;
    float erd = er[n];

    float m = -3.4e38f;
    int   s_c = 0;
    float e_c = 0.f;
    for (int i = beg + lane; i < end; i += 64){
        int s = csrsrc[i];
        if ((unsigned)s >= NN) s = 0;
        float e = el[s] + erd;
        e = (e >= 0.f) ? e : 0.2f * e;
        if (i < beg + 64){ s_c = s; e_c = e; }
        m = fmaxf(m, e);
    }
    #pragma unroll
    for (int off = 32; off; off >>= 1) m = fmaxf(m, __shfl_xor(m, off));

    int jmax = (deg < 64) ? deg : 64;
    float w_c = (lane < jmax) ? __expf(e_c - m) : 0.f;
    float lsum = w_c;
    #pragma unroll
    for (int off = 32; off; off >>= 1) lsum += __shfl_xor(lsum, off);

    const unsigned* ftb = (const unsigned*)ftv;
    float acc0 = 0.f, acc1 = 0.f;
    int j = 0;
    if (jmax >= 8){
        float w[8]; unsigned u[8];
        #pragma unroll
        for (int q = 0; q < 8; q++){
            int s = __builtin_amdgcn_readlane(s_c, q);
            w[q] = rdlanef(w_c, q);
            u[q] = (ftb + s * 64)[lane];
        }
        for (j = 8; j + 8 <= jmax; j += 8){
            float wn[8]; unsigned un[8];
            #pragma unroll
            for (int q = 0; q < 8; q++){
                int s = __builtin_amdgcn_readlane(s_c, j + q);
                wn[q] = rdlanef(w_c, j + q);
                un[q] = (ftb + s * 64)[lane];
            }
            #pragma unroll
            for (int q = 0; q < 8; q++){
                acc0 += w[q] * bflo(u[q]);
                acc1 += w[q] * bfhi(u[q]);
                w[q] = wn[q]; u[q] = un[q];
            }
        }
        #pragma unroll
        for (int q = 0; q < 8; q++){
            acc0 += w[q] * bflo(u[q]);
            acc1 += w[q] * bfhi(u[q]);
        }
    }
    for (; j < jmax; ++j){
        int s = __builtin_amdgcn_readlane(s_c, j);
        float w = rdlanef(w_c, j);
        unsigned u = (ftb + s * 64)[lane];
        acc0 += w * bflo(u); acc1 += w * bfhi(u);
    }
    for (int i = beg + 64; i < end; ++i){
        int s = csrsrc[i];
        if ((unsigned)s >= NN) s = 0;
        float e = el[s] + erd;
        e = (e >= 0.f) ? e : 0.2f * e;
        float w = __expf(e - m);
        unsigned u = (ftb + s * 64)[lane];
        lsum += w;
        acc0 += w * bflo(u); acc1 += w * bfhi(u);
    }
    float inv = 1.f / ((lsum > 0.f) ? lsum : 1.f);
    float o0 = fmaxf(acc0 * inv + ldf(bias, 2 * lane,     isbf), 0.f);
    float o1 = fmaxf(acc1 * inv + ldf(bias, 2 * lane + 1, isbf), 0.f);
    unsigned pk = (unsigned)f2bfu(o0) | ((unsigned)f2bfu(o1) << 16);
    outp[n * 64 + lane] = pk;
}

// ---------------- Aggregation (16 feats, f32 ft): 4-lane edge groups, final output ----------------

__global__ __launch_bounds__(256) void k_agg16(const float* __restrict__ ftv, const float* __restrict__ el,
                                               const float* __restrict__ er, const int* __restrict__ rowptr,
                                               const int* __restrict__ csrsrc, const void* __restrict__ bias,
                                               const int* __restrict__ dflag, void* __restrict__ outp){
    const int isbf = *dflag;
    int lane = threadIdx.x & 63;
    int n = blockIdx.x * 4 + (threadIdx.x >> 6);
    if (n >= NN) return;
    int beg = rowptr[n], end = rowptr[n + 1];
    beg = (beg < 0) ? 0 : (beg > NE ? NE : beg);
    end = (end < beg) ? beg : (end > NE ? NE : end);
    int deg = end - beg;
    float erd = er[n];

    float m = -3.4e38f;
    int   s_c = 0;
    float e_c = 0.f;
    for (int i = beg + lane; i < end; i += 64){
        int s = csrsrc[i];
        if ((unsigned)s >= NN) s = 0;
        float e = el[s] + erd;
        e = (e >= 0.f) ? e : 0.2f * e;
        if (i < beg + 64){ s_c = s; e_c = e; }
        m = fmaxf(m, e);
    }
    #pragma unroll
    for (int off = 32; off; off >>= 1) m = fmaxf(m, __shfl_xor(m, off));

    int jmax = (deg < 64) ? deg : 64;
    float w_c = (lane < jmax) ? __expf(e_c - m) : 0.f;
    float lsum = w_c;
    #pragma unroll
    for (int off = 32; off; off >>= 1) lsum += __shfl_xor(lsum, off);

    const float4* ftq = (const float4*)ftv;   // row n at ftq[n*4 + fl2]
    const int g   = lane >> 2;    // edge-in-batch 0..15
    const int fl2 = lane & 3;
    int nbatch = (jmax + 15) >> 4;    // <= 4
    float wq[4]; float4 uq[4];
    #pragma unroll
    for (int q = 0; q < 4; q++){
        int eidx = (q * 16 + g) & 63;
        int s = __shfl(s_c, eidx);
        wq[q] = (q < nbatch) ? __shfl(w_c, eidx) : 0.f;
        uq[q] = ftq[(unsigned)s * 4 + fl2];
    }
    float a4[4] = {0.f,0.f,0.f,0.f};
    #pragma unroll
    for (int q = 0; q < 4; q++){
        a4[0] += wq[q] * uq[q].x;
        a4[1] += wq[q] * uq[q].y;
        a4[2] += wq[q] * uq[q].z;
        a4[3] += wq[q] * uq[q].w;
    }
    for (int i = beg + 64; i < end; ++i){
        int s = csrsrc[i];
        if ((unsigned)s >= NN) s = 0;
        float e = el[s] + erd;
        e = (e >= 0.f) ? e : 0.2f * e;
        float w = __expf(e - m);
        lsum += w;
        if (g == 0){
            float4 u = ftq[(unsigned)s * 4 + fl2];
            a4[0] += w * u.x; a4[1] += w * u.y; a4[2] += w * u.z; a4[3] += w * u.w;
        }
    }
    #pragma unroll
    for (int i = 0; i < 4; i++){
        a4[i] += __shfl_xor(a4[i], 4);
        a4[i] += __shfl_xor(a4[i], 8);
        a4[i] += __shfl_xor(a4[i], 16);
        a4[i] += __shfl_xor(a4[i], 32);
    }
    float inv = 1.f / ((lsum > 0.f) ? lsum : 1.f);
    if (lane < 4){
        float o0 = fmaxf(a4[0] * inv + ldf(bias, fl2 * 4 + 0, isbf), 0.f);
        float o1 = fmaxf(a4[1] * inv + ldf(bias, fl2 * 4 + 1, isbf), 0.f);
        float o2 = fmaxf(a4[2] * inv + ldf(bias, fl2 * 4 + 2, isbf), 0.f);
        float o3 = fmaxf(a4[3] * inv + ldf(bias, fl2 * 4 + 3, isbf), 0.f);
        if (isbf){
            uint2 pk;
            pk.x = (unsigned)f2bfu(o0) | ((unsigned)f2bfu(o1) << 16);
            pk.y = (unsigned)f2bfu(o2) | ((unsigned)f2bfu(o3) << 16);
            ((uint2*)outp)[n * 4 + fl2] = pk;
        } else {
            float4 o; o.x = o0; o.y = o1; o.z = o2; o.w = o3;
            ((float4*)outp)[n * 4 + fl2] = o;
        }
    }
}

// ---------------- host launch ----------------

static size_t align256(size_t x){ return (x + 255) & ~(size_t)255; }

extern "C" void kernel_launch(void* const* d_in, const int* in_sizes, int n_in,
                              void* d_out, int out_size, void* d_ws, size_t ws_size,
                              hipStream_t stream) {
    const void* feat = d_in[0];
    const int*  src  = (const int*)d_in[1];
    const int*  dst  = (const int*)d_in[2];
    const void* W1 = d_in[3];
    const void* al1= d_in[4];
    const void* ar1= d_in[5];
    const void* b1 = d_in[6];
    const void* W2 = d_in[7];
    const void* al2= d_in[8];
    const void* ar2= d_in[9];
    const void* b2 = d_in[10];
    const void* W3 = d_in[11];
    const void* al3= d_in[12];
    const void* ar3= d_in[13];
    const void* b3 = d_in[14];

    // workspace carve
    char* p = (char*)d_ws;
    size_t off = 0;
    auto carve = [&](size_t bytes)->void*{
        void* r = p + off;
        off += align256(bytes);
        return r;
    };
    float* ftA   = (float*)carve((size_t)NN * FF * 4);   // ft buffer: bf16 view (layers 1/2), f32 view (layer 3)
    unsigned* hB = (unsigned*)carve((size_t)NN * FF * 4); // hidden state bf16-packed; bpairs overlays pre-layer-1
    float* el    = (float*)carve((size_t)NN * 4);
    float* er    = (float*)carve((size_t)NN * 4);
    int*   rowptr= (int*)  carve((size_t)(NN + 1) * 4);
    int*   csrsrc= (int*)  carve((size_t)NE * 4);
    int*   bcounts=(int*)  carve((size_t)NB * 4);
    int*   bbase  =(int*)  carve((size_t)(NB + 1) * 4);
    int*   bh     =(int*)  carve((size_t)NB * NBLK * 4);  // per-(bucket,block) hist/offsets, 800KB
    unsigned short* wtg = (unsigned short*)carve((size_t)34816 * 2);  // W1t,W2t,W3t bf16
    int*   dflag  =(int*)  carve(256);
    unsigned* bpairs = (unsigned*)hB;   // overlay: consumed before hB is first written
    void*  ftb   = ftA;                 // bf16 ft view (layers 1-2); f32 ft3 view (layer 3)
    (void)ws_size; (void)n_in; (void)in_sizes; (void)out_size;

    dim3 b256(256);

    // fused prep: dtype detect + bcounts zero + weight transpose
    k_prep<<<dim3(136), b256, 0, stream>>>((const unsigned short*)feat, W1, W2, W3, dflag, bcounts, wtg);

    // CSR build via hierarchical counting sort
    k_bcount<<<dim3(NBLK), b256, 0, stream>>>(dst, bcounts, bh);
    k_bscan<<<dim3(1), b256, 0, stream>>>(bcounts, bbase, rowptr);
    k_boffset<<<dim3((NB + 3) / 4), b256, 0, stream>>>(bbase, bh);
    k_bucket<<<dim3(NBLK), b256, 0, stream>>>(src, dst, bh, bpairs);
    k_bsort<<<dim3(NB), b256, 0, stream>>>(bpairs, bbase, rowptr, csrsrc);

    const int mg_grid   = (NN + 63) / 64;     // 782
    const int node_grid = (NN + 3) / 4;       // 12500

    // Layer 1: feat @ W1 -> ftb(bf16) + el/er; agg -> hB (bf16-packed)
    k_mgemm<true><<<dim3(mg_grid), b256, 0, stream>>>(feat, wtg, al1, ar1, dflag, (bf16*)ftb, el, er);
    k_agg128<<<dim3(node_grid), b256, 0, stream>>>(ftb, el, er, rowptr, csrsrc, b1, dflag, hB);

    // Layer 2: hB(bf16) @ W2 -> ftb(bf16) + el/er; agg -> hB
    k_mgemm<false><<<dim3(mg_grid), b256, 0, stream>>>(hB, wtg + 16384, al2, ar2, dflag, (bf16*)ftb, el, er);
    k_agg128<<<dim3(node_grid), b256, 0, stream>>>(ftb, el, er, rowptr, csrsrc, b2, dflag, hB);

    // Layer 3: hB(bf16) @ W3 -> ft3(f32) + el/er; agg -> d_out
    k_mgemm3<<<dim3(mg_grid), b256, 0, stream>>>(hB, wtg + 32768, al3, ar3, dflag, (float*)ftb, el, er);
    k_agg16<<<dim3(node_grid), b256, 0, stream>>>((const float*)ftb, el, er, rowptr, csrsrc, b3, dflag, d_out);
}

// Round 16
// 336.728 us; speedup vs baseline: 1.4828x; 1.0093x over previous
//
#include <hip/hip_runtime.h>
#include <hip/hip_bf16.h>

#define NN 50000
#define NE 1600000
#define FF 128
#define CC 16
#define NB ((NN + 63) / 64)       // 782 dst-buckets of 64 nodes
#define NBLK 256                  // partition blocks for the sort (all CUs)
#define CH ((NE + NBLK - 1) / NBLK)   // 6250 edges per partition block

using bf16 = __hip_bfloat16;
using bf16x8 = __attribute__((ext_vector_type(8))) short;   // 8 bf16 = 4 VGPRs
using f32x4  = __attribute__((ext_vector_type(4))) float;

// Runtime-dtype load: isbf selects bf16 vs f32 interpretation of p.
static __device__ __forceinline__ float ldf(const void* p, int i, int isbf){
    return isbf ? __bfloat162float(((const bf16*)p)[i]) : ((const float*)p)[i];
}
static __device__ __forceinline__ float bflo(unsigned u){
    union{unsigned x; float f;} c; c.x = u << 16; return c.f;
}
static __device__ __forceinline__ float bfhi(unsigned u){
    union{unsigned x; float f;} c; c.x = u & 0xFFFF0000u; return c.f;
}
static __device__ __forceinline__ float rdlanef(float v, int l){
    return __int_as_float(__builtin_amdgcn_readlane(__float_as_int(v), l));
}
static __device__ __forceinline__ unsigned short f2bfu(float v){
    bf16 b = __float2bfloat16(v);
    union{bf16 b; unsigned short u;} c; c.b = b; return c.u;
}

// ---------------- fused prep: dtype detect + bcounts zero + W1/W2/W3 transpose->bf16 ----------------
__global__ __launch_bounds__(256) void k_prep(const unsigned short* __restrict__ featu,
                                              const void* __restrict__ W1, const void* __restrict__ W2,
                                              const void* __restrict__ W3, int* __restrict__ dflag,
                                              int* __restrict__ bcounts, unsigned short* __restrict__ wtg){
    __shared__ int cnt;
    const int t = threadIdx.x;
    if (t == 0) cnt = 0;
    __syncthreads();
    unsigned short lo = featu[2 * t];
    int e = (lo >> 7) & 0xFF;
    if (e >= 117 && e <= 137) atomicAdd(&cnt, 1);
    __syncthreads();
    const int isbf = (cnt >= 128) ? 1 : 0;   // 1 => bf16 inputs
    int idx = blockIdx.x * 256 + t;
    if (idx == 0) *dflag = isbf;
    if (idx < NB) bcounts[idx] = 0;
    if (idx < 32768){
        int l = idx >> 14;                   // 0: W1, 1: W2
        int e2 = idx & 16383;
        int f = e2 >> 7, k = e2 & 127;
        const void* W = l ? W2 : W1;
        wtg[idx] = f2bfu(ldf(W, k * FF + f, isbf));
    } else if (idx < 34816){
        int e2 = idx - 32768;                // W3t: 16x128
        int f = e2 >> 7, k = e2 & 127;
        wtg[idx] = f2bfu(ldf(W3, k * CC + f, isbf));
    }
}

// ---------------- CSR build: hierarchical counting sort by dst ----------------

__global__ __launch_bounds__(256) void k_bcount(const int* __restrict__ dst, int* __restrict__ bcounts,
                                                int* __restrict__ bh){
    __shared__ int hist[NB];
    const int t = threadIdx.x, b = blockIdx.x;
    for (int i = t; i < NB; i += 256) hist[i] = 0;
    __syncthreads();
    const int beg = b * CH, end = (beg + CH < NE) ? beg + CH : NE;
    for (int i = beg + t; i < end; i += 256){
        int d = dst[i];
        if ((unsigned)d >= NN) d = 0;
        atomicAdd(&hist[d >> 6], 1);
    }
    __syncthreads();
    for (int k = t; k < NB; k += 256){
        int v = hist[k];
        bh[k * NBLK + b] = v;
        if (v) atomicAdd(&bcounts[k], v);
    }
}

__global__ __launch_bounds__(256) void k_bscan(const int* __restrict__ bcounts, int* __restrict__ bbase,
                                               int* __restrict__ rowptr){
    __shared__ int s[256];
    const int t = threadIdx.x;
    constexpr int PT = (NB + 255) / 256;   // 4
    int loc[PT];
    int sum = 0;
    #pragma unroll
    for (int i = 0; i < PT; i++){
        int idx = t * PT + i;
        int v = (idx < NB) ? bcounts[idx] : 0;
        loc[i] = sum;
        sum += v;
    }
    s[t] = sum; __syncthreads();
    for (int off = 1; off < 256; off <<= 1){
        int x = (t >= off) ? s[t - off] : 0;
        __syncthreads();
        s[t] += x;
        __syncthreads();
    }
    int base = (t > 0) ? s[t - 1] : 0;
    #pragma unroll
    for (int i = 0; i < PT; i++){
        int idx = t * PT + i;
        if (idx < NB) bbase[idx] = base + loc[i];
    }
    if (t == 255){
        bbase[NB] = s[255];      // == NE
        rowptr[NN] = s[255];
    }
}

// Per-bucket offsets: wave-per-bucket shfl scan over the 256 per-block counts (4/lane).
__global__ __launch_bounds__(256) void k_boffset(const int* __restrict__ bbase, int* __restrict__ bh){
    int k = blockIdx.x * 4 + (threadIdx.x >> 6);
    int lane = threadIdx.x & 63;
    if (k >= NB) return;
    int v[4];
    int s = 0;
    #pragma unroll
    for (int i = 0; i < 4; i++){
        v[i] = bh[k * NBLK + 4 * lane + i];
        s += v[i];
    }
    int tot = s;
    #pragma unroll
    for (int off = 1; off < 64; off <<= 1){
        int x = __shfl_up(s, off);
        if (lane >= off) s += x;
    }
    int run = bbase[k] + s - tot;   // exclusive prefix of per-lane sums
    #pragma unroll
    for (int i = 0; i < 4; i++){
        bh[k * NBLK + 4 * lane + i] = run;
        run += v[i];
    }
}

__global__ __launch_bounds__(256) void k_bucket(const int* __restrict__ src, const int* __restrict__ dst,
                                                const int* __restrict__ bh, unsigned* __restrict__ bpairs){
    __shared__ int cur[NB];
    const int t = threadIdx.x, b = blockIdx.x;
    for (int k = t; k < NB; k += 256) cur[k] = bh[k * NBLK + b];
    __syncthreads();
    const int beg = b * CH, end = (beg + CH < NE) ? beg + CH : NE;
    for (int i = beg + t; i < end; i += 256){
        int s = src[i];
        int d = dst[i];
        if ((unsigned)s >= NN) s = 0;
        if ((unsigned)d >= NN) d = 0;
        int p = atomicAdd(&cur[d >> 6], 1);
        if ((unsigned)p < NE) bpairs[p] = (unsigned)s | ((unsigned)(d & 63) << 16);
    }
}

__global__ __launch_bounds__(256) void k_bsort(const unsigned* __restrict__ bpairs, const int* __restrict__ bbase,
                                               int* __restrict__ rowptr, int* __restrict__ csrsrc){
    __shared__ int cnt[64];
    __shared__ int cur[64];
    const int t = threadIdx.x;
    const int b = blockIdx.x;
    const int base = bbase[b];
    const int endb = bbase[b + 1];
    if (t < 64) cnt[t] = 0;
    __syncthreads();
    for (int i = base + t; i < endb; i += 256)
        atomicAdd(&cnt[bpairs[i] >> 16], 1);
    __syncthreads();
    if (t < 64){   // wave 0 exactly: 64-lane exclusive scan via shfl
        int v = cnt[t];
        int inc = v;
        #pragma unroll
        for (int off = 1; off < 64; off <<= 1){
            int x = __shfl_up(inc, off);
            if (t >= off) inc += x;
        }
        int excl = inc - v;
        cur[t] = excl;
        int d = b * 64 + t;
        if (d < NN) rowptr[d] = base + excl;
    }
    __syncthreads();
    for (int i = base + t; i < endb; i += 256){
        unsigned pr = bpairs[i];
        int p = atomicAdd(&cur[pr >> 16], 1);
        csrsrc[base + p] = (int)(pr & 0xFFFFu);
    }
}

// ---------------- MFMA GEMM (layers 1-2), LDS-FREE: fragments loaded straight from global ----------------
// A-frag: 16B of row X[row], offset quad*16 + kt*64 bytes (bf16-packed) — 64 lanes
// cover 16 full cache lines. B-frag: 16B from the 32KB wtg (L1-resident after 1st wave).
// Out-of-range rows clamp to row 0: A-row m only feeds output-row m, discarded by guard.

template<bool XDYN>
__global__ __launch_bounds__(256) void k_mgemm(const void* __restrict__ X, const unsigned short* __restrict__ wtg,
                                               const void* __restrict__ al, const void* __restrict__ ar,
                                               const int* __restrict__ dflag, bf16* __restrict__ ft,
                                               float* __restrict__ el, float* __restrict__ er){
    const int isbf = *dflag;
    const int t  = threadIdx.x;
    const int n0 = blockIdx.x * 64;
    const int wv = t >> 6;
    const int lane = t & 63;
    const int quad = lane >> 4;
    const int mcol = lane & 15;
    const int row = n0 + wv * 16 + mcol;
    const int rc  = (row < NN) ? row : 0;   // clamped A row

    bf16x8 afr[4];
    if (XDYN && !isbf){
        // f32 input: load 8 floats per fragment, convert+pack in-register.
        const float* xr = (const float*)X + rc * FF + quad * 8;
        #pragma unroll
        for (int kt = 0; kt < 4; kt++){
            float4 a = *(const float4*)(xr + kt * 32);
            float4 b = *(const float4*)(xr + kt * 32 + 4);
            union { bf16x8 v; unsigned u[4]; } c;
            c.u[0] = (unsigned)f2bfu(a.x) | ((unsigned)f2bfu(a.y) << 16);
            c.u[1] = (unsigned)f2bfu(a.z) | ((unsigned)f2bfu(a.w) << 16);
            c.u[2] = (unsigned)f2bfu(b.x) | ((unsigned)f2bfu(b.y) << 16);
            c.u[3] = (unsigned)f2bfu(b.z) | ((unsigned)f2bfu(b.w) << 16);
            afr[kt] = c.v;
        }
    } else {
        // bf16-packed rows (bf16 input or bf16 workspace hB).
        const unsigned short* xr = (const unsigned short*)X + rc * FF + quad * 8;
        #pragma unroll
        for (int kt = 0; kt < 4; kt++)
            afr[kt] = *(const bf16x8*)(xr + kt * 32);
    }

    float elp[4] = {0.f,0.f,0.f,0.f}, erp[4] = {0.f,0.f,0.f,0.f};

    #pragma unroll
    for (int f = 0; f < 8; f++){
        f32x4 acc = {0.f, 0.f, 0.f, 0.f};
        const unsigned short* wr = wtg + (f * 16 + mcol) * FF + quad * 8;
        #pragma unroll
        for (int kt = 0; kt < 4; kt++){
            bf16x8 bfr = *(const bf16x8*)(wr + kt * 32);
            acc = __builtin_amdgcn_mfma_f32_16x16x32_bf16(afr[kt], bfr, acc, 0, 0, 0);
        }
        int col = f * 16 + mcol;
        float alv = ldf(al, col, isbf);
        float arv = ldf(ar, col, isbf);
        #pragma unroll
        for (int reg = 0; reg < 4; reg++){
            int node = n0 + wv * 16 + quad * 4 + reg;
            float v = acc[reg];
            if (node < NN) ft[node * FF + col] = __float2bfloat16(v);
            elp[reg] += v * alv;
            erp[reg] += v * arv;
        }
    }

    #pragma unroll
    for (int reg = 0; reg < 4; reg++){
        float pl = elp[reg], pr = erp[reg];
        #pragma unroll
        for (int off = 1; off < 16; off <<= 1){
            pl += __shfl_xor(pl, off);
            pr += __shfl_xor(pr, off);
        }
        int node = n0 + wv * 16 + quad * 4 + reg;
        if (mcol == 0 && node < NN){ el[node] = pl; er[node] = pr; }
    }
}

// ---------------- MFMA GEMM (layer 3), LDS-FREE: ft3 = X(bf16) @ W3, f32 out ----------------

__global__ __launch_bounds__(256) void k_mgemm3(const void* __restrict__ X, const unsigned short* __restrict__ wt3g,
                                                const void* __restrict__ al, const void* __restrict__ ar,
                                                const int* __restrict__ dflag, float* __restrict__ ft,
                                                float* __restrict__ el, float* __restrict__ er){
    const int isbf = *dflag;
    const int t  = threadIdx.x;
    const int n0 = blockIdx.x * 64;
    const int wv = t >> 6;
    const int lane = t & 63;
    const int quad = lane >> 4;
    const int mcol = lane & 15;
    const int row = n0 + wv * 16 + mcol;
    const int rc  = (row < NN) ? row : 0;

    const unsigned short* xr = (const unsigned short*)X + rc * FF + quad * 8;
    const unsigned short* wr = wt3g + mcol * FF + quad * 8;

    f32x4 acc = {0.f, 0.f, 0.f, 0.f};
    #pragma unroll
    for (int kt = 0; kt < 4; kt++){
        bf16x8 afr = *(const bf16x8*)(xr + kt * 32);
        bf16x8 bfr = *(const bf16x8*)(wr + kt * 32);
        acc = __builtin_amdgcn_mfma_f32_16x16x32_bf16(afr, bfr, acc, 0, 0, 0);
    }

    float alv = ldf(al, mcol, isbf);
    float arv = ldf(ar, mcol, isbf);
    #pragma unroll
    for (int reg = 0; reg < 4; reg++){
        int node = n0 + wv * 16 + quad * 4 + reg;
        float v = acc[reg];
        if (node < NN) ft[node * CC + mcol] = v;
        float pl = v * alv, pr = v * arv;
        #pragma unroll
        for (int off = 1; off < 16; off <<= 1){
            pl += __shfl_xor(pl, off);
            pr += __shfl_xor(pr, off);
        }
        if (mcol == 0 && node < NN){ el[node] = pl; er[node] = pr; }
    }
}

// ---------------- Aggregation (128 feats, bf16 ft): round-9 proven kernel, bf16 output ----------------

__global__ __launch_bounds__(256) void k_agg128(const void* __restrict__ ftv, const float* __restrict__ el,
                                                const float* __restrict__ er, const int* __restrict__ rowptr,
                                                const int* __restrict__ csrsrc, const void* __restrict__ bias,
                                                const int* __restrict__ dflag, unsigned* __restrict__ outp){
    const int isbf = *dflag;
    int lane = threadIdx.x & 63;
    int n = blockIdx.x * 4 + (threadIdx.x >> 6);
    if (n >= NN) return;
    int beg = rowptr[n], end = rowptr[n + 1];
    beg = (beg < 0) ? 0 : (beg > NE ? NE : beg);
    end = (end < beg) ? beg : (end > NE ? NE : end);
    int deg = end - beg;
    float erd = er[n];

    float m = -3.4e38f;
    int   s_c = 0;
    float e_c = 0.f;
    for (int i = beg + lane; i < end; i += 64){
        int s = csrsrc[i];
        if ((unsigned)s >= NN) s = 0;
        float e = el[s] + erd;
        e = (e >= 0.f) ? e : 0.2f * e;
        if (i < beg + 64){ s_c = s; e_c = e; }
        m = fmaxf(m, e);
    }
    #pragma unroll
    for (int off = 32; off; off >>= 1) m = fmaxf(m, __shfl_xor(m, off));

    int jmax = (deg < 64) ? deg : 64;
    float w_c = (lane < jmax) ? __expf(e_c - m) : 0.f;
    float lsum = w_c;
    #pragma unroll
    for (int off = 32; off; off >>= 1) lsum += __shfl_xor(lsum, off);

    const unsigned* ftb = (const unsigned*)ftv;
    float acc0 = 0.f, acc1 = 0.f;
    int j = 0;
    if (jmax >= 8){
        float w[8]; unsigned u[8];
        #pragma unroll
        for (int q = 0; q < 8; q++){
            int s = __builtin_amdgcn_readlane(s_c, q);
            w[q] = rdlanef(w_c, q);
            u[q] = (ftb + s * 64)[lane];
        }
        for (j = 8; j + 8 <= jmax; j += 8){
            float wn[8]; unsigned un[8];
            #pragma unroll
            for (int q = 0; q < 8; q++){
                int s = __builtin_amdgcn_readlane(s_c, j + q);
                wn[q] = rdlanef(w_c, j + q);
                un[q] = (ftb + s * 64)[lane];
            }
            #pragma unroll
            for (int q = 0; q < 8; q++){
                acc0 += w[q] * bflo(u[q]);
                acc1 += w[q] * bfhi(u[q]);
                w[q] = wn[q]; u[q] = un[q];
            }
        }
        #pragma unroll
        for (int q = 0; q < 8; q++){
            acc0 += w[q] * bflo(u[q]);
            acc1 += w[q] * bfhi(u[q]);
        }
    }
    for (; j < jmax; ++j){
        int s = __builtin_amdgcn_readlane(s_c, j);
        float w = rdlanef(w_c, j);
        unsigned u = (ftb + s * 64)[lane];
        acc0 += w * bflo(u); acc1 += w * bfhi(u);
    }
    for (int i = beg + 64; i < end; ++i){
        int s = csrsrc[i];
        if ((unsigned)s >= NN) s = 0;
        float e = el[s] + erd;
        e = (e >= 0.f) ? e : 0.2f * e;
        float w = __expf(e - m);
        unsigned u = (ftb + s * 64)[lane];
        lsum += w;
        acc0 += w * bflo(u); acc1 += w * bfhi(u);
    }
    float inv = 1.f / ((lsum > 0.f) ? lsum : 1.f);
    float o0 = fmaxf(acc0 * inv + ldf(bias, 2 * lane,     isbf), 0.f);
    float o1 = fmaxf(acc1 * inv + ldf(bias, 2 * lane + 1, isbf), 0.f);
    unsigned pk = (unsigned)f2bfu(o0) | ((unsigned)f2bfu(o1) << 16);
    outp[n * 64 + lane] = pk;
}

// ---------------- Aggregation (16 feats, f32 ft): 4-lane edge groups, final output ----------------

__global__ __launch_bounds__(256) void k_agg16(const float* __restrict__ ftv, const float* __restrict__ el,
                                               const float* __restrict__ er, const int* __restrict__ rowptr,
                                               const int* __restrict__ csrsrc, const void* __restrict__ bias,
                                               const int* __restrict__ dflag, void* __restrict__ outp){
    const int isbf = *dflag;
    int lane = threadIdx.x & 63;
    int n = blockIdx.x * 4 + (threadIdx.x >> 6);
    if (n >= NN) return;
    int beg = rowptr[n], end = rowptr[n + 1];
    beg = (beg < 0) ? 0 : (beg > NE ? NE : beg);
    end = (end < beg) ? beg : (end > NE ? NE : end);
    int deg = end - beg;
    float erd = er[n];

    float m = -3.4e38f;
    int   s_c = 0;
    float e_c = 0.f;
    for (int i = beg + lane; i < end; i += 64){
        int s = csrsrc[i];
        if ((unsigned)s >= NN) s = 0;
        float e = el[s] + erd;
        e = (e >= 0.f) ? e : 0.2f * e;
        if (i < beg + 64){ s_c = s; e_c = e; }
        m = fmaxf(m, e);
    }
    #pragma unroll
    for (int off = 32; off; off >>= 1) m = fmaxf(m, __shfl_xor(m, off));

    int jmax = (deg < 64) ? deg : 64;
    float w_c = (lane < jmax) ? __expf(e_c - m) : 0.f;
    float lsum = w_c;
    #pragma unroll
    for (int off = 32; off; off >>= 1) lsum += __shfl_xor(lsum, off);

    const float4* ftq = (const float4*)ftv;   // row n at ftq[n*4 + fl2]
    const int g   = lane >> 2;    // edge-in-batch 0..15
    const int fl2 = lane & 3;
    int nbatch = (jmax + 15) >> 4;    // <= 4
    float wq[4]; float4 uq[4];
    #pragma unroll
    for (int q = 0; q < 4; q++){
        int eidx = (q * 16 + g) & 63;
        int s = __shfl(s_c, eidx);
        wq[q] = (q < nbatch) ? __shfl(w_c, eidx) : 0.f;
        uq[q] = ftq[(unsigned)s * 4 + fl2];
    }
    float a4[4] = {0.f,0.f,0.f,0.f};
    #pragma unroll
    for (int q = 0; q < 4; q++){
        a4[0] += wq[q] * uq[q].x;
        a4[1] += wq[q] * uq[q].y;
        a4[2] += wq[q] * uq[q].z;
        a4[3] += wq[q] * uq[q].w;
    }
    for (int i = beg + 64; i < end; ++i){
        int s = csrsrc[i];
        if ((unsigned)s >= NN) s = 0;
        float e = el[s] + erd;
        e = (e >= 0.f) ? e : 0.2f * e;
        float w = __expf(e - m);
        lsum += w;
        if (g == 0){
            float4 u = ftq[(unsigned)s * 4 + fl2];
            a4[0] += w * u.x; a4[1] += w * u.y; a4[2] += w * u.z; a4[3] += w * u.w;
        }
    }
    #pragma unroll
    for (int i = 0; i < 4; i++){
        a4[i] += __shfl_xor(a4[i], 4);
        a4[i] += __shfl_xor(a4[i], 8);
        a4[i] += __shfl_xor(a4[i], 16);
        a4[i] += __shfl_xor(a4[i], 32);
    }
    float inv = 1.f / ((lsum > 0.f) ? lsum : 1.f);
    if (lane < 4){
        float o0 = fmaxf(a4[0] * inv + ldf(bias, fl2 * 4 + 0, isbf), 0.f);
        float o1 = fmaxf(a4[1] * inv + ldf(bias, fl2 * 4 + 1, isbf), 0.f);
        float o2 = fmaxf(a4[2] * inv + ldf(bias, fl2 * 4 + 2, isbf), 0.f);
        float o3 = fmaxf(a4[3] * inv + ldf(bias, fl2 * 4 + 3, isbf), 0.f);
        if (isbf){
            uint2 pk;
            pk.x = (unsigned)f2bfu(o0) | ((unsigned)f2bfu(o1) << 16);
            pk.y = (unsigned)f2bfu(o2) | ((unsigned)f2bfu(o3) << 16);
            ((uint2*)outp)[n * 4 + fl2] = pk;
        } else {
            float4 o; o.x = o0; o.y = o1; o.z = o2; o.w = o3;
            ((float4*)outp)[n * 4 + fl2] = o;
        }
    }
}

// ---------------- host launch ----------------

static size_t align256(size_t x){ return (x + 255) & ~(size_t)255; }

extern "C" void kernel_launch(void* const* d_in, const int* in_sizes, int n_in,
                              void* d_out, int out_size, void* d_ws, size_t ws_size,
                              hipStream_t stream) {
    const void* feat = d_in[0];
    const int*  src  = (const int*)d_in[1];
    const int*  dst  = (const int*)d_in[2];
    const void* W1 = d_in[3];
    const void* al1= d_in[4];
    const void* ar1= d_in[5];
    const void* b1 = d_in[6];
    const void* W2 = d_in[7];
    const void* al2= d_in[8];
    const void* ar2= d_in[9];
    const void* b2 = d_in[10];
    const void* W3 = d_in[11];
    const void* al3= d_in[12];
    const void* ar3= d_in[13];
    const void* b3 = d_in[14];

    // workspace carve
    char* p = (char*)d_ws;
    size_t off = 0;
    auto carve = [&](size_t bytes)->void*{
        void* r = p + off;
        off += align256(bytes);
        return r;
    };
    float* ftA   = (float*)carve((size_t)NN * FF * 4);   // ft buffer: bf16 view (layers 1/2), f32 view (layer 3)
    unsigned* hB = (unsigned*)carve((size_t)NN * FF * 4); // hidden state bf16-packed; bpairs overlays pre-layer-1
    float* el    = (float*)carve((size_t)NN * 4);
    float* er    = (float*)carve((size_t)NN * 4);
    int*   rowptr= (int*)  carve((size_t)(NN + 1) * 4);
    int*   csrsrc= (int*)  carve((size_t)NE * 4);
    int*   bcounts=(int*)  carve((size_t)NB * 4);
    int*   bbase  =(int*)  carve((size_t)(NB + 1) * 4);
    int*   bh     =(int*)  carve((size_t)NB * NBLK * 4);  // per-(bucket,block) hist/offsets, 800KB
    unsigned short* wtg = (unsigned short*)carve((size_t)34816 * 2);  // W1t,W2t,W3t bf16
    int*   dflag  =(int*)  carve(256);
    unsigned* bpairs = (unsigned*)hB;   // overlay: consumed before hB is first written
    void*  ftb   = ftA;                 // bf16 ft view (layers 1-2); f32 ft3 view (layer 3)
    (void)ws_size; (void)n_in; (void)in_sizes; (void)out_size;

    dim3 b256(256);

    // fused prep: dtype detect + bcounts zero + weight transpose
    k_prep<<<dim3(136), b256, 0, stream>>>((const unsigned short*)feat, W1, W2, W3, dflag, bcounts, wtg);

    // CSR build via hierarchical counting sort
    k_bcount<<<dim3(NBLK), b256, 0, stream>>>(dst, bcounts, bh);
    k_bscan<<<dim3(1), b256, 0, stream>>>(bcounts, bbase, rowptr);
    k_boffset<<<dim3((NB + 3) / 4), b256, 0, stream>>>(bbase, bh);
    k_bucket<<<dim3(NBLK), b256, 0, stream>>>(src, dst, bh, bpairs);
    k_bsort<<<dim3(NB), b256, 0, stream>>>(bpairs, bbase, rowptr, csrsrc);

    const int mg_grid   = (NN + 63) / 64;     // 782
    const int node_grid = (NN + 3) / 4;       // 12500

    // Layer 1: feat @ W1 -> ftb(bf16) + el/er; agg -> hB (bf16-packed)
    k_mgemm<true><<<dim3(mg_grid), b256, 0, stream>>>(feat, wtg, al1, ar1, dflag, (bf16*)ftb, el, er);
    k_agg128<<<dim3(node_grid), b256, 0, stream>>>(ftb, el, er, rowptr, csrsrc, b1, dflag, hB);

    // Layer 2: hB(bf16) @ W2 -> ftb(bf16) + el/er; agg -> hB
    k_mgemm<false><<<dim3(mg_grid), b256, 0, stream>>>(hB, wtg + 16384, al2, ar2, dflag, (bf16*)ftb, el, er);
    k_agg128<<<dim3(node_grid), b256, 0, stream>>>(ftb, el, er, rowptr, csrsrc, b2, dflag, hB);

    // Layer 3: hB(bf16) @ W3 -> ft3(f32) + el/er; agg -> d_out
    k_mgemm3<<<dim3(mg_grid), b256, 0, stream>>>(hB, wtg + 32768, al3, ar3, dflag, (float*)ftb, el, er);
    k_agg16<<<dim3(node_grid), b256, 0, stream>>>((const float*)ftb, el, er, rowptr, csrsrc, b3, dflag, d_out);
}